// Round 12
// baseline (1445.262 us; speedup 1.0000x reference)
//
#include <hip/hip_runtime.h>

// ---------------------------------------------------------------------------
// GCKAN (3 layers) on MI355X — round 14.
// ea_gemm9: 512-thread (8-wave) merged edge GEMM over the same 64-edge tile.
// Per-thread acc drops 136->68 regs (each wave owns one 64-col panel slice;
// Wo split into 8 per-wave pieces), A tile shared in LDS by all 8 waves,
// B direct-to-register. __launch_bounds__(512,4) -> 4 waves/SIMD
// (2 co-resident blocks/CU), double round-13's parallelism.
// ---------------------------------------------------------------------------

typedef __attribute__((ext_vector_type(4))) float f32x4;
typedef __attribute__((ext_vector_type(8))) short bf16x8;
typedef __attribute__((ext_vector_type(8))) unsigned short u16x8;
typedef __attribute__((ext_vector_type(4))) unsigned short u16x4;

__device__ __forceinline__ unsigned short f2bf(float f) {
    union { float f; unsigned u; } v; v.f = f;
    unsigned r = v.u + 0x7FFFu + ((v.u >> 16) & 1u);
    return (unsigned short)(r >> 16);
}

__device__ __forceinline__ float bf2f(unsigned short u) {
    union { unsigned u; float f; } v; v.u = ((unsigned)u) << 16;
    return v.f;
}

__device__ __forceinline__ float siluf(float x) {
    return x / (1.0f + __expf(-x));
}

// Expand scalar x -> 8 channels [silu, B0..B6]; cubic B-spline on uniform
// knots t_i = 0.5 i - 2.5 (matches reference Cox-de Boor exactly).
__device__ __forceinline__ void expand8(float x, float* o8) {
    float b[10];
#pragma unroll
    for (int i = 0; i < 10; ++i) {
        float ti = 0.5f * i - 2.5f;
        b[i] = (x >= ti && x < ti + 0.5f) ? 1.0f : 0.0f;
    }
#pragma unroll
    for (int j = 1; j <= 3; ++j) {
        float inv = 2.0f / (float)j;
#pragma unroll
        for (int i = 0; i < 10 - j; ++i) {
            float ti = 0.5f * i - 2.5f;
            float tj = 0.5f * (i + j + 1) - 2.5f;
            b[i] = (x - ti) * inv * b[i] + (tj - x) * inv * b[i + 1];
        }
    }
    o8[0] = siluf(x);
#pragma unroll
    for (int c = 0; c < 7; ++c) o8[c + 1] = b[c];
}

// ---------------------------------------------------------------------------
// Edge counting sort by destination (col).
// ---------------------------------------------------------------------------
__global__ __launch_bounds__(256) void k_hist(
    const int* __restrict__ col, int* __restrict__ cnt, int E) {
    int i = blockIdx.x * 256 + threadIdx.x;
    if (i < E) atomicAdd(&cnt[col[i]], 1);
}

__global__ __launch_bounds__(1024) void k_scan(int* __restrict__ c, int N) {
    __shared__ int wsum[16];
    __shared__ int ctot;
    const int t = threadIdx.x;
    const int lane = t & 63, wid = t >> 6;
    int carry = 0;
    for (int base = 0; base < N; base += 1024) {
        int i = base + t;
        int v0 = (i < N) ? c[i] : 0;
        int v = v0;
#pragma unroll
        for (int off = 1; off < 64; off <<= 1) {
            int n = __shfl_up(v, (unsigned)off, 64);
            if (lane >= off) v += n;
        }
        if (lane == 63) wsum[wid] = v;
        __syncthreads();
        if (t < 16) {
            int s = wsum[t], sv = s;
#pragma unroll
            for (int off = 1; off < 16; off <<= 1) {
                int n = __shfl_up(sv, (unsigned)off, 16);
                if (t >= off) sv += n;
            }
            wsum[t] = sv - s;
            if (t == 15) ctot = sv;
        }
        __syncthreads();
        if (i < N) c[i] = carry + wsum[wid] + v - v0;
        carry += ctot;
        __syncthreads();
    }
}

__global__ __launch_bounds__(256) void k_scatter(
    const int* __restrict__ row, const int* __restrict__ col,
    int* __restrict__ cursor, int* __restrict__ rowS,
    int* __restrict__ colS, int* __restrict__ eidS, int E) {
    int i = blockIdx.x * 256 + threadIdx.x;
    if (i < E) {
        int c = col[i];
        int p = atomicAdd(&cursor[c], 1);
        rowS[p] = row[i];
        colS[p] = c;
        eidS[p] = i;
    }
}

// ---------------------------------------------------------------------------
// Weight prep: pack [N][K] f32 -> K-step-tiled bf16:
//   dst[(( (k>>5)*4 + ((k>>3)&3) )*N + n)*8 + (k&7)]
// ---------------------------------------------------------------------------
__global__ __launch_bounds__(256) void pack_kt(
    const float* __restrict__ src, unsigned short* __restrict__ dst,
    int N, int K) {
    long idx = (long)blockIdx.x * 256 + threadIdx.x;
    if (idx >= (long)N * K) return;
    int n = (int)(idx / K), k = (int)(idx - (long)n * K);
    long o = (((long)(k >> 5) * 4 + ((k >> 3) & 3)) * N + n) * 8 + (k & 7);
    dst[o] = f2bf(src[idx]);
}

__global__ __launch_bounds__(256) void pack_kan_kt(
    const float* __restrict__ baseW, const float* __restrict__ splineW,
    unsigned short* __restrict__ dst, int N) {
    long idx = (long)blockIdx.x * 256 + threadIdx.x;   // n*2048 + k
    if (idx >= (long)N * 2048) return;
    int n = (int)(idx >> 11), k = (int)(idx & 2047);
    int ic = k >> 3, c = k & 7;
    float v = (c == 0) ? baseW[(long)n * 256 + ic]
                       : splineW[((long)n * 256 + ic) * 7 + (c - 1)];
    long o = (((long)(k >> 5) * 4 + ((k >> 3) & 3)) * N + n) * 8 + (k & 7);
    dst[o] = f2bf(v);
}

// ---------------------------------------------------------------------------
// ea_gemm9: 8-wave merged edge GEMM, 64-edge tile.
// Wave w<4 -> W0 cols [64w,64w+64); wave w>=4 -> W1 cols [64(w-4),..).
// Wo (64x32) split into 8 pieces: wave w computes rows 16*(w&3), col frag
// (w>>2). A tile in LDS shared by all waves; depth-2 A reg pipeline
// (one float4/thread/step). B direct-to-register from packed weights.
// ---------------------------------------------------------------------------
template <bool TWO, bool WITH_O>
__global__ __launch_bounds__(512, 4) void ea_gemm9(
    const float* __restrict__ EA,
    const unsigned short* __restrict__ Wp0, const float* __restrict__ b0,
    const unsigned short* __restrict__ Wp1, const float* __restrict__ b1,
    const unsigned short* __restrict__ Wpo, const float* __restrict__ bo,
    unsigned short* __restrict__ O0, unsigned short* __restrict__ O1,
    unsigned short* __restrict__ Oo, int E) {
    __shared__ __align__(16) char smem[8192];   // A dbuf 2x4KB

    const int tid = threadIdx.x;
    const int wv = tid >> 6, lane = tid & 63;
    const int l15 = lane & 15, l4 = lane >> 4;
    const long m0 = (long)blockIdx.x * 64;

    f32x4 acc[16] = {};
    f32x4 acco = {};

    // A staging: thread covers row sr, k in [4*sg, 4*sg+4)
    const int sr = tid >> 3, sg = tid & 7;
    const long arow = m0 + sr;
    const bool aok = arow < E;
    const float* aptr = EA + arow * 384 + sg * 4;
    const int gg = sg >> 1;
    const int awoff = gg * 1024 + (sr ^ (gg << 2)) * 16 + (sg & 1) * 8;

    const char* bp = (const char*)((TWO && wv >= 4) ? Wp1 : Wp0) +
                     l4 * 4096 + (wv & 3) * 1024 + l15 * 16;
    const char* bpo = (const char*)Wpo + l4 * 512 + ((wv >> 2) * 16 + l15) * 16;
    // LDS offset of this wave's Wo A-fragment (mi = wv&3), swizzled
    const int aooff = l4 * 1024 + (((wv & 3) * 16 + l15) ^ (l4 << 2)) * 16;

#define WRITE_A9(IT, V)                                                        \
    {                                                                          \
        u16x4 rr = {};                                                         \
        if (aok) {                                                             \
            rr[0] = f2bf((V).x); rr[1] = f2bf((V).y);                          \
            rr[2] = f2bf((V).z); rr[3] = f2bf((V).w);                          \
        }                                                                      \
        *(u16x4*)(smem + ((IT) & 1) * 4096 + awoff) = rr;                      \
    }

    // ---- prologue: A(0) -> LDS; A(1),A(2) -> reg sets ----
    const float4 z4 = make_float4(0.f, 0.f, 0.f, 0.f);
    {
        float4 s0 = z4;
        if (aok) s0 = *(const float4*)(aptr);
        WRITE_A9(0, s0);
    }
    float4 rs1 = z4, rs0 = z4;
    if (aok) {
        rs1 = *(const float4*)(aptr + 32);
        rs0 = *(const float4*)(aptr + 64);
    }

#pragma unroll
    for (int it = 0; it < 12; ++it) {
        asm volatile("s_waitcnt lgkmcnt(0)" ::: "memory");
        __builtin_amdgcn_s_barrier();
        __builtin_amdgcn_sched_barrier(0);

        if (it < 11) {
            if ((it + 1) & 1) { WRITE_A9(it + 1, rs1); }
            else              { WRITE_A9(it + 1, rs0); }
            if (it <= 8) {
                if ((it + 3) & 1) {
                    if (aok) rs1 = *(const float4*)(aptr + (it + 3) * 32);
                } else {
                    if (aok) rs0 = *(const float4*)(aptr + (it + 3) * 32);
                }
            }
        }

        // ---- compute step it ----
        const int buf = it & 1;
        bf16x8 af[4];
#pragma unroll
        for (int mi = 0; mi < 4; ++mi)
            af[mi] = *(const bf16x8*)(smem + buf * 4096 + l4 * 1024 +
                                      (((mi * 16 + l15) ^ (l4 << 2))) * 16);
        bf16x8 bfv[4];
#pragma unroll
        for (int nj = 0; nj < 4; ++nj)
            bfv[nj] = *(const bf16x8*)(bp + (long)it * 16384 + nj * 256);
#pragma unroll
        for (int mi = 0; mi < 4; ++mi)
#pragma unroll
            for (int nj = 0; nj < 4; ++nj)
                acc[mi * 4 + nj] = __builtin_amdgcn_mfma_f32_16x16x32_bf16(
                    af[mi], bfv[nj], acc[mi * 4 + nj], 0, 0, 0);
        if (WITH_O) {
            bf16x8 aw = *(const bf16x8*)(smem + buf * 4096 + aooff);
            bf16x8 bov = *(const bf16x8*)(bpo + (long)it * 2048);
            acco = __builtin_amdgcn_mfma_f32_16x16x32_bf16(aw, bov, acco, 0, 0, 0);
        }
    }
#undef WRITE_A9

    // ---- epilogue: bias + bf16 store, original order (linear) ----
    const int nb2 = (wv & 3) * 64;
    if (TWO || wv < 4) {
        const float* bb = (TWO && wv >= 4) ? b1 : b0;
        unsigned short* OO = (TWO && wv >= 4) ? O1 : O0;
        float bs[4];
#pragma unroll
        for (int nj = 0; nj < 4; ++nj) bs[nj] = bb[nb2 + nj * 16 + l15];
#pragma unroll
        for (int mi = 0; mi < 4; ++mi) {
#pragma unroll
            for (int r = 0; r < 4; ++r) {
                long e = m0 + mi * 16 + l4 * 4 + r;
                if (e < E) {
                    unsigned short* dst = OO + e * 256 + nb2 + l15;
#pragma unroll
                    for (int nj = 0; nj < 4; ++nj)
                        dst[nj * 16] = f2bf(acc[mi * 4 + nj][r] + bs[nj]);
                }
            }
        }
    }
    if (WITH_O) {
        const int oc = (wv >> 2) * 16 + l15;
        const float bso = bo[oc];
#pragma unroll
        for (int r = 0; r < 4; ++r) {
            long e = m0 + (wv & 3) * 16 + l4 * 4 + r;
            if (e < E) Oo[e * 32 + oc] = f2bf(acco[r] + bso);
        }
    }
}

// ---------------------------------------------------------------------------
// KAN linear N=256, B direct-to-register: Y = expand8(AGG)(M,2048) @ Wc^T.
// ---------------------------------------------------------------------------
__global__ __launch_bounds__(256, 2) void kan_mfma256_r(
    const float* __restrict__ AGG, const unsigned short* __restrict__ Wp,
    float* __restrict__ Y, int M) {
    __shared__ __align__(16) char smem[8192];
    const int tid = threadIdx.x;
    const int wv = tid >> 6, lane = tid & 63;
    const int l15 = lane & 15, l4 = lane >> 4;
    const long m0 = (long)blockIdx.x * 64;
    f32x4 acc[4][4] = {};

    const int srow = tid & 63, sg = tid >> 6;
    const long arow = m0 + srow;
    const bool aok = arow < M;
    const float* aptr = AGG + arow * 256 + sg;
    const int awoff = sg * 1024 + srow * 16;
    const char* bp = (const char*)Wp + l4 * 4096 + wv * 1024 + l15 * 16;

    {
        float xv0 = aok ? aptr[0] : 0.f;
        float e8[8];
        expand8(xv0, e8);
        u16x8 ap;
#pragma unroll
        for (int c = 0; c < 8; ++c) ap[c] = f2bf(e8[c]);
        *(u16x8*)(smem + awoff) = ap;
    }
    float xv1 = aok ? aptr[4] : 0.f;

    for (int it = 0; it < 64; ++it) {
        asm volatile("s_waitcnt lgkmcnt(0)" ::: "memory");
        __builtin_amdgcn_s_barrier();
        __builtin_amdgcn_sched_barrier(0);
        const int buf = it & 1;
        if (it < 63) {
            float e8[8];
            expand8(xv1, e8);
            u16x8 ap;
#pragma unroll
            for (int c = 0; c < 8; ++c) ap[c] = f2bf(e8[c]);
            *(u16x8*)(smem + (buf ^ 1) * 4096 + awoff) = ap;
            if (it < 62) xv1 = aok ? aptr[(it + 2) * 4] : 0.f;
        }
        bf16x8 af[4], bfv[4];
#pragma unroll
        for (int mi = 0; mi < 4; ++mi)
            af[mi] = *(const bf16x8*)(smem + buf * 4096 + l4 * 1024 +
                                      (mi * 16 + l15) * 16);
#pragma unroll
        for (int nj = 0; nj < 4; ++nj)
            bfv[nj] = *(const bf16x8*)(bp + (long)it * 16384 + nj * 256);
#pragma unroll
        for (int mi = 0; mi < 4; ++mi)
#pragma unroll
            for (int nj = 0; nj < 4; ++nj)
                acc[mi][nj] = __builtin_amdgcn_mfma_f32_16x16x32_bf16(
                    af[mi], bfv[nj], acc[mi][nj], 0, 0, 0);
    }

    const int nb = wv * 64;
#pragma unroll
    for (int mi = 0; mi < 4; ++mi) {
#pragma unroll
        for (int r = 0; r < 4; ++r) {
            long gm = m0 + mi * 16 + l4 * 4 + r;
            if (gm < M) {
#pragma unroll
                for (int nj = 0; nj < 4; ++nj)
                    Y[gm * 256 + nb + nj * 16 + l15] = acc[mi][nj][r];
            }
        }
    }
}

// ---------------------------------------------------------------------------
// Node GEMM N=256, B direct-to-register: Y(bf16) = X(M,K)@W^T + bias.
// ---------------------------------------------------------------------------
template <int K>
__global__ __launch_bounds__(256, 2) void node_mfma_r(
    const float* __restrict__ X, const unsigned short* __restrict__ Wp,
    const float* __restrict__ bias, unsigned short* __restrict__ Y, int M) {
    __shared__ __align__(16) char smem[8192];
    const int tid = threadIdx.x;
    const int wv = tid >> 6, lane = tid & 63;
    const int l15 = lane & 15, l4 = lane >> 4;
    const long m0 = (long)blockIdx.x * 64;
    f32x4 acc[4][4] = {};
    constexpr int NIT = K / 32;

    const int sr = tid >> 2, sg = tid & 3;
    const long arow = m0 + sr;
    const bool aok = arow < M;
    const float* aptr = X + arow * K + sg * 8;
    const int awoff = sg * 1024 + ((sr ^ (sg << 2))) * 16;
    const char* bp = (const char*)Wp + l4 * 4096 + wv * 1024 + l15 * 16;

#define WRITE_NA8(IT, VA, VB)                                                  \
    {                                                                          \
        u16x8 rr = {};                                                         \
        if (aok) {                                                             \
            rr[0] = f2bf((VA).x); rr[1] = f2bf((VA).y);                        \
            rr[2] = f2bf((VA).z); rr[3] = f2bf((VA).w);                        \
            rr[4] = f2bf((VB).x); rr[5] = f2bf((VB).y);                        \
            rr[6] = f2bf((VB).z); rr[7] = f2bf((VB).w);                        \
        }                                                                      \
        *(u16x8*)(smem + ((IT) & 1) * 4096 + awoff) = rr;                      \
    }

    const float4 z4 = make_float4(0.f, 0.f, 0.f, 0.f);
    {
        float4 s0 = z4, s1 = z4;
        if (aok) { s0 = *(const float4*)(aptr); s1 = *(const float4*)(aptr + 4); }
        WRITE_NA8(0, s0, s1);
    }
    float4 r1a = z4, r1b = z4, r0a = z4, r0b = z4;
    if (aok) {
        r1a = *(const float4*)(aptr + 32); r1b = *(const float4*)(aptr + 36);
        r0a = *(const float4*)(aptr + 64); r0b = *(const float4*)(aptr + 68);
    }

#pragma unroll
    for (int it = 0; it < NIT; ++it) {
        asm volatile("s_waitcnt lgkmcnt(0)" ::: "memory");
        __builtin_amdgcn_s_barrier();
        __builtin_amdgcn_sched_barrier(0);
        if (it < NIT - 1) {
            if ((it + 1) & 1) { WRITE_NA8(it + 1, r1a, r1b); }
            else              { WRITE_NA8(it + 1, r0a, r0b); }
            if (it <= NIT - 4) {
                if ((it + 3) & 1) {
                    if (aok) {
                        r1a = *(const float4*)(aptr + (it + 3) * 32);
                        r1b = *(const float4*)(aptr + (it + 3) * 32 + 4);
                    }
                } else {
                    if (aok) {
                        r0a = *(const float4*)(aptr + (it + 3) * 32);
                        r0b = *(const float4*)(aptr + (it + 3) * 32 + 4);
                    }
                }
            }
        }
        const int buf = it & 1;
        bf16x8 af[4], bfv[4];
#pragma unroll
        for (int mi = 0; mi < 4; ++mi)
            af[mi] = *(const bf16x8*)(smem + buf * 4096 + l4 * 1024 +
                                      (((mi * 16 + l15) ^ (l4 << 2))) * 16);
#pragma unroll
        for (int nj = 0; nj < 4; ++nj)
            bfv[nj] = *(const bf16x8*)(bp + (long)it * 16384 + nj * 256);
#pragma unroll
        for (int mi = 0; mi < 4; ++mi)
#pragma unroll
            for (int nj = 0; nj < 4; ++nj)
                acc[mi][nj] = __builtin_amdgcn_mfma_f32_16x16x32_bf16(
                    af[mi], bfv[nj], acc[mi][nj], 0, 0, 0);
    }
#undef WRITE_NA8

    const int nb = wv * 64;
    float bs[4];
#pragma unroll
    for (int nj = 0; nj < 4; ++nj) bs[nj] = bias[nb + nj * 16 + l15];
#pragma unroll
    for (int mi = 0; mi < 4; ++mi) {
#pragma unroll
        for (int r = 0; r < 4; ++r) {
            long gm = m0 + mi * 16 + l4 * 4 + r;
            if (gm < M) {
#pragma unroll
                for (int nj = 0; nj < 4; ++nj)
                    Y[gm * 256 + nb + nj * 16 + l15] = f2bf(acc[mi][nj][r] + bs[nj]);
            }
        }
    }
}

// ---------------------------------------------------------------------------
// Message+reduce, N=256 (gather via eidS; register run-accumulation).
// ---------------------------------------------------------------------------
__global__ __launch_bounds__(256) void msg256(
    const unsigned short* __restrict__ EAr, const unsigned short* __restrict__ XT,
    const int* __restrict__ rowS, const int* __restrict__ colS,
    const int* __restrict__ eidS, float* __restrict__ AGG, int E) {
    __shared__ __align__(16) unsigned short eas[64][264];
    __shared__ int rows_s[64];
    __shared__ int cols_s[64];
    const int tid = threadIdx.x;
    const long m0 = (long)blockIdx.x * 64;

    const int r = tid >> 2, s = tid & 3;
    {
        long p = m0 + r;
        if (p < E) {
            const unsigned short* src = EAr + (long)eidS[p] * 256 + s * 8;
#pragma unroll
            for (int k = 0; k < 8; ++k)
                *(u16x8*)&eas[r][s * 8 + k * 32] = *(const u16x8*)(src + k * 32);
        } else {
            u16x8 z = {};
#pragma unroll
            for (int k = 0; k < 8; ++k) *(u16x8*)&eas[r][s * 8 + k * 32] = z;
        }
    }
    if (tid < 64) {
        long p = m0 + tid;
        cols_s[tid] = (p < E) ? colS[p] : -1;
        rows_s[tid] = (p < E) ? rowS[p] : 0;
    }
    __syncthreads();

    const int c = tid;
    float sum = 0.f;
    int cur = cols_s[0];
    int runstart = 0;
#pragma unroll 1
    for (int g = 0; g < 8; ++g) {
        float xv[8];
#pragma unroll
        for (int j = 0; j < 8; ++j)
            xv[j] = bf2f(XT[(long)rows_s[g * 8 + j] * 256 + c]);
#pragma unroll
        for (int j = 0; j < 8; ++j) {
            int e = g * 8 + j;
            int cc = cols_s[e];
            if (cc != cur) {
                if (cur >= 0) {
                    float* dst = AGG + (long)cur * 256 + c;
                    if (runstart > 0) *dst = sum;
                    else atomicAdd(dst, sum);
                }
                cur = cc; runstart = e; sum = 0.f;
            }
            sum += bf2f(eas[e][c]) * xv[j];
        }
    }
    if (cur >= 0) {
        atomicAdd(AGG + (long)cur * 256 + c, sum);
    }
}

// ---------------------------------------------------------------------------
// Message+reduce, N=32 (output layer).
// ---------------------------------------------------------------------------
__global__ __launch_bounds__(256) void msg32(
    const unsigned short* __restrict__ EAro, const unsigned short* __restrict__ XT,
    const int* __restrict__ rowS, const int* __restrict__ colS,
    const int* __restrict__ eidS, float* __restrict__ AGG, int E) {
    __shared__ __align__(16) unsigned short eas[256][36];
    __shared__ int rows_s[256];
    __shared__ int cols_s[256];
    __shared__ int eid_s[256];
    const int tid = threadIdx.x;
    const long m0 = (long)blockIdx.x * 256;

    {
        long p = m0 + tid;
        cols_s[tid] = (p < E) ? colS[p] : -1;
        rows_s[tid] = (p < E) ? rowS[p] : 0;
        eid_s[tid]  = (p < E) ? eidS[p] : -1;
    }
    __syncthreads();
    const int rr0 = tid >> 2, s = tid & 3;
#pragma unroll
    for (int ps = 0; ps < 4; ++ps) {
        int rr = ps * 64 + rr0;
        int eid = eid_s[rr];
        u16x8 v = {};
        if (eid >= 0) v = *(const u16x8*)(EAro + (long)eid * 32 + s * 8);
        *(u16x8*)&eas[rr][s * 8] = v;
    }
    __syncthreads();

    const int c = tid & 31, sb = tid >> 5;
    const int e0 = sb * 32;
    float sum = 0.f;
    int cur = cols_s[e0];
    int runstart = e0;
#pragma unroll 1
    for (int g = 0; g < 4; ++g) {
        float xv[8];
#pragma unroll
        for (int j = 0; j < 8; ++j)
            xv[j] = bf2f(XT[(long)rows_s[e0 + g * 8 + j] * 32 + c]);
#pragma unroll
        for (int j = 0; j < 8; ++j) {
            int e = e0 + g * 8 + j;
            int cc = cols_s[e];
            if (cc != cur) {
                if (cur >= 0) {
                    float* dst = AGG + (long)cur * 32 + c;
                    if (runstart > 0 && cols_s[runstart - 1] != cur) *dst = sum;
                    else atomicAdd(dst, sum);
                }
                cur = cc; runstart = e; sum = 0.f;
            }
            sum += bf2f(eas[e][c]) * xv[j];
        }
    }
    if (cur >= 0) {
        int eend = e0 + 32;
        float* dst = AGG + (long)cur * 32 + c;
        bool oks = (runstart > 0 && cols_s[runstart - 1] != cur);
        bool oke = (eend < 256 && cols_s[eend] != cur);
        if (oks && oke) *dst = sum;
        else atomicAdd(dst, sum);
    }
}

// ---------------------------------------------------------------------------
// Node GEMM for concat input, N=32.
// ---------------------------------------------------------------------------
__global__ __launch_bounds__(256) void node_cat_mfma(
    const float* __restrict__ X, const float* __restrict__ H0,
    const float* __restrict__ H1, const unsigned short* __restrict__ Wh,
    const float* __restrict__ bias, unsigned short* __restrict__ Y, int M) {
    __shared__ __align__(16) unsigned short As[4][256][8];
    __shared__ __align__(16) unsigned short Bs[4][32][8];
    const int tid = threadIdx.x;
    const int wv = tid >> 6, lane = tid & 63;
    const int l15 = lane & 15, l4 = lane >> 4;
    const long m0 = (long)blockIdx.x * 256;
    f32x4 acc[4][2] = {};

    const int sr = tid >> 3;
    const int sq = (tid & 7) * 4;
    const int sg2 = sq >> 3, so2 = sq & 7;

    for (int it = 0; it < 24; ++it) {
        const int k0 = it * 32;
        const float* src = (it < 8) ? X : (it < 16) ? H0 : H1;
        const int kk = k0 & 255;
        float4 va[8];
#pragma unroll
        for (int j = 0; j < 8; ++j) {
            long r_ = m0 + j * 32 + sr;
            va[j] = (r_ < M) ? *(const float4*)(src + r_ * 256 + kk + sq)
                             : make_float4(0.f, 0.f, 0.f, 0.f);
        }
        u16x8 bv = {};
        if (tid < 128)
            bv = *(const u16x8*)(Wh + (long)(tid >> 2) * 768 + k0 + (tid & 3) * 8);
        __syncthreads();
#pragma unroll
        for (int j = 0; j < 8; ++j) {
            u16x4 ap;
            ap[0] = f2bf(va[j].x); ap[1] = f2bf(va[j].y);
            ap[2] = f2bf(va[j].z); ap[3] = f2bf(va[j].w);
            *(u16x4*)&As[sg2][j * 32 + sr][so2] = ap;
        }
        if (tid < 128) *(u16x8*)&Bs[tid & 3][tid >> 2][0] = bv;
        __syncthreads();
        bf16x8 af[4], bfv[2];
#pragma unroll
        for (int mi = 0; mi < 4; ++mi)
            af[mi] = *(const bf16x8*)&As[l4][wv * 64 + mi * 16 + l15][0];
#pragma unroll
        for (int nj = 0; nj < 2; ++nj)
            bfv[nj] = *(const bf16x8*)&Bs[l4][nj * 16 + l15][0];
#pragma unroll
        for (int mi = 0; mi < 4; ++mi)
#pragma unroll
            for (int nj = 0; nj < 2; ++nj)
                acc[mi][nj] = __builtin_amdgcn_mfma_f32_16x16x32_bf16(
                    af[mi], bfv[nj], acc[mi][nj], 0, 0, 0);
    }

#pragma unroll
    for (int mi = 0; mi < 4; ++mi) {
#pragma unroll
        for (int r = 0; r < 4; ++r) {
            long gm = m0 + wv * 64 + mi * 16 + l4 * 4 + r;
            if (gm < M) {
#pragma unroll
                for (int nj = 0; nj < 2; ++nj) {
                    int o = nj * 16 + l15;
                    Y[gm * 32 + o] = f2bf(acc[mi][nj][r] + bias[o]);
                }
            }
        }
    }
}

// ---------------------------------------------------------------------------
// Small f32 KAN for output layer (M x 32 -> M x 32).
// ---------------------------------------------------------------------------
__global__ __launch_bounds__(256) void kan_gemm32(
    const float* __restrict__ AGG, const float* __restrict__ Wc,
    float* __restrict__ Y, int M) {
    __shared__ float As[64][36];
    __shared__ float Bs[32][36];
    const int tid = threadIdx.x;
    const int tx = tid & 15, ty = tid >> 4;
    const int m0 = blockIdx.x * 64;
    float acc[4][2] = {{0.f, 0.f}, {0.f, 0.f}, {0.f, 0.f}, {0.f, 0.f}};
    const int er = tid >> 2, ef = tid & 3;
    const int em = m0 + er;
    for (int ic = 0; ic < 32; ic += 4) {
        float xv = (em < M) ? AGG[(long)em * 32 + ic + ef] : 0.f;
        float e8[8];
        expand8(xv, e8);
        *(float4*)&As[er][ef * 8] = make_float4(e8[0], e8[1], e8[2], e8[3]);
        *(float4*)&As[er][ef * 8 + 4] = make_float4(e8[4], e8[5], e8[6], e8[7]);
        {
            int o = tid >> 3, k4 = (tid & 7) * 4;
            *(float4*)&Bs[o][k4] = *(const float4*)&Wc[(long)o * 256 + ic * 8 + k4];
        }
        __syncthreads();
#pragma unroll
        for (int kk = 0; kk < 32; ++kk) {
            float a_[4], b_[2];
#pragma unroll
            for (int i = 0; i < 4; ++i) a_[i] = As[ty * 4 + i][kk];
#pragma unroll
            for (int j = 0; j < 2; ++j) b_[j] = Bs[tx * 2 + j][kk];
#pragma unroll
            for (int i = 0; i < 4; ++i)
#pragma unroll
                for (int j = 0; j < 2; ++j) acc[i][j] = fmaf(a_[i], b_[j], acc[i][j]);
        }
        __syncthreads();
    }
#pragma unroll
    for (int i = 0; i < 4; ++i) {
        int gm = m0 + ty * 4 + i;
        if (gm >= M) continue;
#pragma unroll
        for (int j = 0; j < 2; ++j) Y[(long)gm * 32 + tx * 2 + j] = acc[i][j];
    }
}

// ---------------------------------------------------------------------------
// Misc weight prep
// ---------------------------------------------------------------------------
__global__ __launch_bounds__(256) void cvt_bf16(
    const float* __restrict__ s, unsigned short* __restrict__ d, int n) {
    int i = blockIdx.x * 256 + threadIdx.x;
    if (i < n) d[i] = f2bf(s[i]);
}

__global__ __launch_bounds__(256) void pack_kan_f32(
    const float* __restrict__ baseW, const float* __restrict__ splineW,
    float* __restrict__ Wc, int n) {
    int idx = blockIdx.x * 256 + threadIdx.x;
    if (idx >= n) return;
    float* dst = Wc + (long)idx * 8;
    dst[0] = baseW[idx];
    const float* sw = splineW + (long)idx * 7;
#pragma unroll
    for (int c = 0; c < 7; ++c) dst[1 + c] = sw[c];
}

// ---------------------------------------------------------------------------
extern "C" void kernel_launch(void* const* d_in, const int* in_sizes, int n_in,
                              void* d_out, int out_size, void* d_ws, size_t ws_size,
                              hipStream_t stream) {
    const float* x          = (const float*)d_in[0];
    const int*   edge_index = (const int*)d_in[1];
    const float* edge_attr  = (const float*)d_in[2];
    const float* node_W0 = (const float*)d_in[3];
    const float* node_b0 = (const float*)d_in[4];
    const float* edge_W0 = (const float*)d_in[5];
    const float* edge_b0 = (const float*)d_in[6];
    const float* base_W0 = (const float*)d_in[7];
    const float* spline_W0 = (const float*)d_in[8];
    const float* node_W1 = (const float*)d_in[9];
    const float* node_b1 = (const float*)d_in[10];
    const float* edge_W1 = (const float*)d_in[11];
    const float* edge_b1 = (const float*)d_in[12];
    const float* base_W1 = (const float*)d_in[13];
    const float* spline_W1 = (const float*)d_in[14];
    const float* node_Wo = (const float*)d_in[15];
    const float* node_bo = (const float*)d_in[16];
    const float* edge_Wo = (const float*)d_in[17];
    const float* edge_bo = (const float*)d_in[18];
    const float* base_Wo = (const float*)d_in[19];
    const float* spline_Wo = (const float*)d_in[20];
    float* out = (float*)d_out;

    const int N = in_sizes[0] / 256;
    const int E = in_sizes[1] / 2;

    float* ws  = (float*)d_ws;
    unsigned short* xt = (unsigned short*)ws;  // bf16 XT (slot sized N*256 f32)
    float* agg = ws + (long)N * 256;           // N*256 f32
    float* h0  = agg + (long)N * 256;
    float* h1  = h0 + (long)N * 256;
    float* Wco = h1 + (long)N * 256;           // 32*256 f32
    unsigned short* Wp0  = (unsigned short*)(Wco + 32 * 256);  // 98304
    unsigned short* Wp1  = Wp0 + 98304;
    unsigned short* Wpo  = Wp1 + 98304;                        // 12288
    unsigned short* nWp0 = Wpo + 12288;                        // 65536
    unsigned short* nWp1 = nWp0 + 65536;
    unsigned short* Wc0p = nWp1 + 65536;                       // 524288
    unsigned short* Wc1p = Wc0p + 524288;
    unsigned short* nWoh = Wc1p + 524288;                      // 24576
    int* cursor = (int*)(nWoh + 24576);
    int* rowS   = cursor + (N + 1);
    int* colS   = rowS + E;
    int* eidS   = colS + E;
    unsigned short* EAr0 = (unsigned short*)(((uintptr_t)(eidS + E) + 255) & ~(uintptr_t)255);
    const int nt256 = (E + 255) / 256;
    const long Epad = (long)nt256 * 256;
    unsigned short* EAr1 = EAr0 + Epad * 256;

    const size_t need2 = (size_t)((char*)(EAr1 + Epad * 256 + Epad * 32) - (char*)d_ws);
    const bool two = ws_size >= need2;
    unsigned short* EAro = two ? (EAr1 + Epad * 256) : (EAr0 + Epad * 256);

    const int* row = edge_index;
    const int* col = edge_index + E;

    const int nb64 = (N + 63) / 64;
    const int eb64 = (E + 63) / 64;
    const int eb256 = (E + 255) / 256;
    const int nb256 = (N + 255) / 256;

    // ---- counting sort of edges by destination ----
    hipMemsetAsync(cursor, 0, (size_t)(N + 1) * sizeof(int), stream);
    k_hist<<<eb256, 256, 0, stream>>>(col, cursor, E);
    k_scan<<<1, 1024, 0, stream>>>(cursor, N);
    k_scatter<<<eb256, 256, 0, stream>>>(row, col, cursor, rowS, colS, eidS, E);

    // ---- weight prep: K-step-tiled packs ----
    pack_kt<<<(256 * 384 + 255) / 256, 256, 0, stream>>>(edge_W0, Wp0, 256, 384);
    pack_kt<<<(256 * 384 + 255) / 256, 256, 0, stream>>>(edge_W1, Wp1, 256, 384);
    pack_kt<<<(32 * 384 + 255) / 256, 256, 0, stream>>>(edge_Wo, Wpo, 32, 384);
    pack_kt<<<(256 * 256 + 255) / 256, 256, 0, stream>>>(node_W0, nWp0, 256, 256);
    pack_kt<<<(256 * 256 + 255) / 256, 256, 0, stream>>>(node_W1, nWp1, 256, 256);
    pack_kan_kt<<<(256 * 2048 + 255) / 256, 256, 0, stream>>>(base_W0, spline_W0, Wc0p, 256);
    pack_kan_kt<<<(256 * 2048 + 255) / 256, 256, 0, stream>>>(base_W1, spline_W1, Wc1p, 256);
    cvt_bf16<<<(32 * 768 + 255) / 256, 256, 0, stream>>>(node_Wo, nWoh, 32 * 768);
    pack_kan_f32<<<(32 * 32 + 255) / 256, 256, 0, stream>>>(base_Wo, spline_Wo, Wco, 32 * 32);

    // ---- edge GEMMs (8-wave blocks, B direct-to-register) ----
    if (two) {
        ea_gemm9<true, true><<<eb64, 512, 0, stream>>>(
            edge_attr, Wp0, edge_b0, Wp1, edge_b1, Wpo, edge_bo,
            EAr0, EAr1, EAro, E);
    } else {
        ea_gemm9<false, true><<<eb64, 512, 0, stream>>>(
            edge_attr, Wp0, edge_b0, Wp0, edge_b0, Wpo, edge_bo,
            EAr0, EAr0, EAro, E);
    }

    // ---- layer 0 ----
    hipMemsetAsync(agg, 0, (size_t)N * 256 * sizeof(float), stream);
    node_mfma_r<256><<<nb64, 256, 0, stream>>>(x, nWp0, node_b0, xt, N);
    msg256<<<eb64, 256, 0, stream>>>(EAr0, xt, rowS, colS, eidS, agg, E);
    kan_mfma256_r<<<nb64, 256, 0, stream>>>(agg, Wc0p, h0, N);

    // ---- layer 1 ----
    if (!two) {
        ea_gemm9<false, false><<<eb64, 512, 0, stream>>>(
            edge_attr, Wp1, edge_b1, Wp1, edge_b1, Wpo, edge_bo,
            EAr0, EAr0, EAro, E);
    }
    hipMemsetAsync(agg, 0, (size_t)N * 256 * sizeof(float), stream);
    node_mfma_r<256><<<nb64, 256, 0, stream>>>(h0, nWp1, node_b1, xt, N);
    msg256<<<eb64, 256, 0, stream>>>(two ? EAr1 : EAr0, xt, rowS, colS, eidS, agg, E);
    kan_mfma256_r<<<nb64, 256, 0, stream>>>(agg, Wc1p, h1, N);

    // ---- output layer ----
    hipMemsetAsync(agg, 0, (size_t)N * 32 * sizeof(float), stream);
    node_cat_mfma<<<nb256, 256, 0, stream>>>(x, h0, h1, nWoh, node_bo, xt, N);
    msg32<<<eb256, 256, 0, stream>>>(EAro, xt, rowS, colS, eidS, agg, E);
    kan_gemm32<<<nb64, 256, 0, stream>>>(agg, Wco, out, N);
}

// Round 13
// 1419.333 us; speedup vs baseline: 1.0183x; 1.0183x over previous
//
#include <hip/hip_runtime.h>

// ---------------------------------------------------------------------------
// GCKAN (3 layers) on MI355X — round 15.
// Round-14's 8-wave ea_gemm9 spilled: __launch_bounds__(512,4) capped VGPRs
// at 64 (< the ~110 working set) -> acc spilled to scratch (+0.5GB HBM
// traffic, VGPR_Count=64). Fix: __launch_bounds__(512,2) -> 128-VGPR cap,
// same 2-blocks/CU occupancy target, no spills. Everything else unchanged.
// ---------------------------------------------------------------------------

typedef __attribute__((ext_vector_type(4))) float f32x4;
typedef __attribute__((ext_vector_type(8))) short bf16x8;
typedef __attribute__((ext_vector_type(8))) unsigned short u16x8;
typedef __attribute__((ext_vector_type(4))) unsigned short u16x4;

__device__ __forceinline__ unsigned short f2bf(float f) {
    union { float f; unsigned u; } v; v.f = f;
    unsigned r = v.u + 0x7FFFu + ((v.u >> 16) & 1u);
    return (unsigned short)(r >> 16);
}

__device__ __forceinline__ float bf2f(unsigned short u) {
    union { unsigned u; float f; } v; v.u = ((unsigned)u) << 16;
    return v.f;
}

__device__ __forceinline__ float siluf(float x) {
    return x / (1.0f + __expf(-x));
}

// Expand scalar x -> 8 channels [silu, B0..B6]; cubic B-spline on uniform
// knots t_i = 0.5 i - 2.5 (matches reference Cox-de Boor exactly).
__device__ __forceinline__ void expand8(float x, float* o8) {
    float b[10];
#pragma unroll
    for (int i = 0; i < 10; ++i) {
        float ti = 0.5f * i - 2.5f;
        b[i] = (x >= ti && x < ti + 0.5f) ? 1.0f : 0.0f;
    }
#pragma unroll
    for (int j = 1; j <= 3; ++j) {
        float inv = 2.0f / (float)j;
#pragma unroll
        for (int i = 0; i < 10 - j; ++i) {
            float ti = 0.5f * i - 2.5f;
            float tj = 0.5f * (i + j + 1) - 2.5f;
            b[i] = (x - ti) * inv * b[i] + (tj - x) * inv * b[i + 1];
        }
    }
    o8[0] = siluf(x);
#pragma unroll
    for (int c = 0; c < 7; ++c) o8[c + 1] = b[c];
}

// ---------------------------------------------------------------------------
// Edge counting sort by destination (col).
// ---------------------------------------------------------------------------
__global__ __launch_bounds__(256) void k_hist(
    const int* __restrict__ col, int* __restrict__ cnt, int E) {
    int i = blockIdx.x * 256 + threadIdx.x;
    if (i < E) atomicAdd(&cnt[col[i]], 1);
}

__global__ __launch_bounds__(1024) void k_scan(int* __restrict__ c, int N) {
    __shared__ int wsum[16];
    __shared__ int ctot;
    const int t = threadIdx.x;
    const int lane = t & 63, wid = t >> 6;
    int carry = 0;
    for (int base = 0; base < N; base += 1024) {
        int i = base + t;
        int v0 = (i < N) ? c[i] : 0;
        int v = v0;
#pragma unroll
        for (int off = 1; off < 64; off <<= 1) {
            int n = __shfl_up(v, (unsigned)off, 64);
            if (lane >= off) v += n;
        }
        if (lane == 63) wsum[wid] = v;
        __syncthreads();
        if (t < 16) {
            int s = wsum[t], sv = s;
#pragma unroll
            for (int off = 1; off < 16; off <<= 1) {
                int n = __shfl_up(sv, (unsigned)off, 16);
                if (t >= off) sv += n;
            }
            wsum[t] = sv - s;
            if (t == 15) ctot = sv;
        }
        __syncthreads();
        if (i < N) c[i] = carry + wsum[wid] + v - v0;
        carry += ctot;
        __syncthreads();
    }
}

__global__ __launch_bounds__(256) void k_scatter(
    const int* __restrict__ row, const int* __restrict__ col,
    int* __restrict__ cursor, int* __restrict__ rowS,
    int* __restrict__ colS, int* __restrict__ eidS, int E) {
    int i = blockIdx.x * 256 + threadIdx.x;
    if (i < E) {
        int c = col[i];
        int p = atomicAdd(&cursor[c], 1);
        rowS[p] = row[i];
        colS[p] = c;
        eidS[p] = i;
    }
}

// ---------------------------------------------------------------------------
// Weight prep: pack [N][K] f32 -> K-step-tiled bf16:
//   dst[(( (k>>5)*4 + ((k>>3)&3) )*N + n)*8 + (k&7)]
// ---------------------------------------------------------------------------
__global__ __launch_bounds__(256) void pack_kt(
    const float* __restrict__ src, unsigned short* __restrict__ dst,
    int N, int K) {
    long idx = (long)blockIdx.x * 256 + threadIdx.x;
    if (idx >= (long)N * K) return;
    int n = (int)(idx / K), k = (int)(idx - (long)n * K);
    long o = (((long)(k >> 5) * 4 + ((k >> 3) & 3)) * N + n) * 8 + (k & 7);
    dst[o] = f2bf(src[idx]);
}

__global__ __launch_bounds__(256) void pack_kan_kt(
    const float* __restrict__ baseW, const float* __restrict__ splineW,
    unsigned short* __restrict__ dst, int N) {
    long idx = (long)blockIdx.x * 256 + threadIdx.x;   // n*2048 + k
    if (idx >= (long)N * 2048) return;
    int n = (int)(idx >> 11), k = (int)(idx & 2047);
    int ic = k >> 3, c = k & 7;
    float v = (c == 0) ? baseW[(long)n * 256 + ic]
                       : splineW[((long)n * 256 + ic) * 7 + (c - 1)];
    long o = (((long)(k >> 5) * 4 + ((k >> 3) & 3)) * N + n) * 8 + (k & 7);
    dst[o] = f2bf(v);
}

// ---------------------------------------------------------------------------
// ea_gemm9: 8-wave merged edge GEMM, 64-edge tile.
// Wave w<4 -> W0 cols [64w,64w+64); wave w>=4 -> W1 cols [64(w-4),..).
// Wo (64x32) split into 8 pieces: wave w computes rows 16*(w&3), col frag
// (w>>2). A tile in LDS shared by all waves; depth-2 A reg pipeline
// (one float4/thread/step). B direct-to-register from packed weights.
// __launch_bounds__(512,2): 128-VGPR cap, 2 blocks/CU, no spills.
// ---------------------------------------------------------------------------
template <bool TWO, bool WITH_O>
__global__ __launch_bounds__(512, 2) void ea_gemm9(
    const float* __restrict__ EA,
    const unsigned short* __restrict__ Wp0, const float* __restrict__ b0,
    const unsigned short* __restrict__ Wp1, const float* __restrict__ b1,
    const unsigned short* __restrict__ Wpo, const float* __restrict__ bo,
    unsigned short* __restrict__ O0, unsigned short* __restrict__ O1,
    unsigned short* __restrict__ Oo, int E) {
    __shared__ __align__(16) char smem[8192];   // A dbuf 2x4KB

    const int tid = threadIdx.x;
    const int wv = tid >> 6, lane = tid & 63;
    const int l15 = lane & 15, l4 = lane >> 4;
    const long m0 = (long)blockIdx.x * 64;

    f32x4 acc[16] = {};
    f32x4 acco = {};

    // A staging: thread covers row sr, k in [4*sg, 4*sg+4)
    const int sr = tid >> 3, sg = tid & 7;
    const long arow = m0 + sr;
    const bool aok = arow < E;
    const float* aptr = EA + arow * 384 + sg * 4;
    const int gg = sg >> 1;
    const int awoff = gg * 1024 + (sr ^ (gg << 2)) * 16 + (sg & 1) * 8;

    const char* bp = (const char*)((TWO && wv >= 4) ? Wp1 : Wp0) +
                     l4 * 4096 + (wv & 3) * 1024 + l15 * 16;
    const char* bpo = (const char*)Wpo + l4 * 512 + ((wv >> 2) * 16 + l15) * 16;
    // LDS offset of this wave's Wo A-fragment (mi = wv&3), swizzled
    const int aooff = l4 * 1024 + (((wv & 3) * 16 + l15) ^ (l4 << 2)) * 16;

#define WRITE_A9(IT, V)                                                        \
    {                                                                          \
        u16x4 rr = {};                                                         \
        if (aok) {                                                             \
            rr[0] = f2bf((V).x); rr[1] = f2bf((V).y);                          \
            rr[2] = f2bf((V).z); rr[3] = f2bf((V).w);                          \
        }                                                                      \
        *(u16x4*)(smem + ((IT) & 1) * 4096 + awoff) = rr;                      \
    }

    // ---- prologue: A(0) -> LDS; A(1),A(2) -> reg sets ----
    const float4 z4 = make_float4(0.f, 0.f, 0.f, 0.f);
    {
        float4 s0 = z4;
        if (aok) s0 = *(const float4*)(aptr);
        WRITE_A9(0, s0);
    }
    float4 rs1 = z4, rs0 = z4;
    if (aok) {
        rs1 = *(const float4*)(aptr + 32);
        rs0 = *(const float4*)(aptr + 64);
    }

#pragma unroll
    for (int it = 0; it < 12; ++it) {
        asm volatile("s_waitcnt lgkmcnt(0)" ::: "memory");
        __builtin_amdgcn_s_barrier();
        __builtin_amdgcn_sched_barrier(0);

        if (it < 11) {
            if ((it + 1) & 1) { WRITE_A9(it + 1, rs1); }
            else              { WRITE_A9(it + 1, rs0); }
            if (it <= 8) {
                if ((it + 3) & 1) {
                    if (aok) rs1 = *(const float4*)(aptr + (it + 3) * 32);
                } else {
                    if (aok) rs0 = *(const float4*)(aptr + (it + 3) * 32);
                }
            }
        }

        // ---- compute step it ----
        const int buf = it & 1;
        bf16x8 af[4];
#pragma unroll
        for (int mi = 0; mi < 4; ++mi)
            af[mi] = *(const bf16x8*)(smem + buf * 4096 + l4 * 1024 +
                                      (((mi * 16 + l15) ^ (l4 << 2))) * 16);
        bf16x8 bfv[4];
#pragma unroll
        for (int nj = 0; nj < 4; ++nj)
            bfv[nj] = *(const bf16x8*)(bp + (long)it * 16384 + nj * 256);
#pragma unroll
        for (int mi = 0; mi < 4; ++mi)
#pragma unroll
            for (int nj = 0; nj < 4; ++nj)
                acc[mi * 4 + nj] = __builtin_amdgcn_mfma_f32_16x16x32_bf16(
                    af[mi], bfv[nj], acc[mi * 4 + nj], 0, 0, 0);
        if (WITH_O) {
            bf16x8 aw = *(const bf16x8*)(smem + buf * 4096 + aooff);
            bf16x8 bov = *(const bf16x8*)(bpo + (long)it * 2048);
            acco = __builtin_amdgcn_mfma_f32_16x16x32_bf16(aw, bov, acco, 0, 0, 0);
        }
    }
#undef WRITE_A9

    // ---- epilogue: bias + bf16 store, original order (linear) ----
    const int nb2 = (wv & 3) * 64;
    if (TWO || wv < 4) {
        const float* bb = (TWO && wv >= 4) ? b1 : b0;
        unsigned short* OO = (TWO && wv >= 4) ? O1 : O0;
        float bs[4];
#pragma unroll
        for (int nj = 0; nj < 4; ++nj) bs[nj] = bb[nb2 + nj * 16 + l15];
#pragma unroll
        for (int mi = 0; mi < 4; ++mi) {
#pragma unroll
            for (int r = 0; r < 4; ++r) {
                long e = m0 + mi * 16 + l4 * 4 + r;
                if (e < E) {
                    unsigned short* dst = OO + e * 256 + nb2 + l15;
#pragma unroll
                    for (int nj = 0; nj < 4; ++nj)
                        dst[nj * 16] = f2bf(acc[mi * 4 + nj][r] + bs[nj]);
                }
            }
        }
    }
    if (WITH_O) {
        const int oc = (wv >> 2) * 16 + l15;
        const float bso = bo[oc];
#pragma unroll
        for (int r = 0; r < 4; ++r) {
            long e = m0 + (wv & 3) * 16 + l4 * 4 + r;
            if (e < E) Oo[e * 32 + oc] = f2bf(acco[r] + bso);
        }
    }
}

// ---------------------------------------------------------------------------
// KAN linear N=256, B direct-to-register: Y = expand8(AGG)(M,2048) @ Wc^T.
// ---------------------------------------------------------------------------
__global__ __launch_bounds__(256, 2) void kan_mfma256_r(
    const float* __restrict__ AGG, const unsigned short* __restrict__ Wp,
    float* __restrict__ Y, int M) {
    __shared__ __align__(16) char smem[8192];
    const int tid = threadIdx.x;
    const int wv = tid >> 6, lane = tid & 63;
    const int l15 = lane & 15, l4 = lane >> 4;
    const long m0 = (long)blockIdx.x * 64;
    f32x4 acc[4][4] = {};

    const int srow = tid & 63, sg = tid >> 6;
    const long arow = m0 + srow;
    const bool aok = arow < M;
    const float* aptr = AGG + arow * 256 + sg;
    const int awoff = sg * 1024 + srow * 16;
    const char* bp = (const char*)Wp + l4 * 4096 + wv * 1024 + l15 * 16;

    {
        float xv0 = aok ? aptr[0] : 0.f;
        float e8[8];
        expand8(xv0, e8);
        u16x8 ap;
#pragma unroll
        for (int c = 0; c < 8; ++c) ap[c] = f2bf(e8[c]);
        *(u16x8*)(smem + awoff) = ap;
    }
    float xv1 = aok ? aptr[4] : 0.f;

    for (int it = 0; it < 64; ++it) {
        asm volatile("s_waitcnt lgkmcnt(0)" ::: "memory");
        __builtin_amdgcn_s_barrier();
        __builtin_amdgcn_sched_barrier(0);
        const int buf = it & 1;
        if (it < 63) {
            float e8[8];
            expand8(xv1, e8);
            u16x8 ap;
#pragma unroll
            for (int c = 0; c < 8; ++c) ap[c] = f2bf(e8[c]);
            *(u16x8*)(smem + (buf ^ 1) * 4096 + awoff) = ap;
            if (it < 62) xv1 = aok ? aptr[(it + 2) * 4] : 0.f;
        }
        bf16x8 af[4], bfv[4];
#pragma unroll
        for (int mi = 0; mi < 4; ++mi)
            af[mi] = *(const bf16x8*)(smem + buf * 4096 + l4 * 1024 +
                                      (mi * 16 + l15) * 16);
#pragma unroll
        for (int nj = 0; nj < 4; ++nj)
            bfv[nj] = *(const bf16x8*)(bp + (long)it * 16384 + nj * 256);
#pragma unroll
        for (int mi = 0; mi < 4; ++mi)
#pragma unroll
            for (int nj = 0; nj < 4; ++nj)
                acc[mi][nj] = __builtin_amdgcn_mfma_f32_16x16x32_bf16(
                    af[mi], bfv[nj], acc[mi][nj], 0, 0, 0);
    }

    const int nb = wv * 64;
#pragma unroll
    for (int mi = 0; mi < 4; ++mi) {
#pragma unroll
        for (int r = 0; r < 4; ++r) {
            long gm = m0 + mi * 16 + l4 * 4 + r;
            if (gm < M) {
#pragma unroll
                for (int nj = 0; nj < 4; ++nj)
                    Y[gm * 256 + nb + nj * 16 + l15] = acc[mi][nj][r];
            }
        }
    }
}

// ---------------------------------------------------------------------------
// Node GEMM N=256, B direct-to-register: Y(bf16) = X(M,K)@W^T + bias.
// ---------------------------------------------------------------------------
template <int K>
__global__ __launch_bounds__(256, 2) void node_mfma_r(
    const float* __restrict__ X, const unsigned short* __restrict__ Wp,
    const float* __restrict__ bias, unsigned short* __restrict__ Y, int M) {
    __shared__ __align__(16) char smem[8192];
    const int tid = threadIdx.x;
    const int wv = tid >> 6, lane = tid & 63;
    const int l15 = lane & 15, l4 = lane >> 4;
    const long m0 = (long)blockIdx.x * 64;
    f32x4 acc[4][4] = {};
    constexpr int NIT = K / 32;

    const int sr = tid >> 2, sg = tid & 3;
    const long arow = m0 + sr;
    const bool aok = arow < M;
    const float* aptr = X + arow * K + sg * 8;
    const int awoff = sg * 1024 + ((sr ^ (sg << 2))) * 16;
    const char* bp = (const char*)Wp + l4 * 4096 + wv * 1024 + l15 * 16;

#define WRITE_NA8(IT, VA, VB)                                                  \
    {                                                                          \
        u16x8 rr = {};                                                         \
        if (aok) {                                                             \
            rr[0] = f2bf((VA).x); rr[1] = f2bf((VA).y);                        \
            rr[2] = f2bf((VA).z); rr[3] = f2bf((VA).w);                        \
            rr[4] = f2bf((VB).x); rr[5] = f2bf((VB).y);                        \
            rr[6] = f2bf((VB).z); rr[7] = f2bf((VB).w);                        \
        }                                                                      \
        *(u16x8*)(smem + ((IT) & 1) * 4096 + awoff) = rr;                      \
    }

    const float4 z4 = make_float4(0.f, 0.f, 0.f, 0.f);
    {
        float4 s0 = z4, s1 = z4;
        if (aok) { s0 = *(const float4*)(aptr); s1 = *(const float4*)(aptr + 4); }
        WRITE_NA8(0, s0, s1);
    }
    float4 r1a = z4, r1b = z4, r0a = z4, r0b = z4;
    if (aok) {
        r1a = *(const float4*)(aptr + 32); r1b = *(const float4*)(aptr + 36);
        r0a = *(const float4*)(aptr + 64); r0b = *(const float4*)(aptr + 68);
    }

#pragma unroll
    for (int it = 0; it < NIT; ++it) {
        asm volatile("s_waitcnt lgkmcnt(0)" ::: "memory");
        __builtin_amdgcn_s_barrier();
        __builtin_amdgcn_sched_barrier(0);
        if (it < NIT - 1) {
            if ((it + 1) & 1) { WRITE_NA8(it + 1, r1a, r1b); }
            else              { WRITE_NA8(it + 1, r0a, r0b); }
            if (it <= NIT - 4) {
                if ((it + 3) & 1) {
                    if (aok) {
                        r1a = *(const float4*)(aptr + (it + 3) * 32);
                        r1b = *(const float4*)(aptr + (it + 3) * 32 + 4);
                    }
                } else {
                    if (aok) {
                        r0a = *(const float4*)(aptr + (it + 3) * 32);
                        r0b = *(const float4*)(aptr + (it + 3) * 32 + 4);
                    }
                }
            }
        }
        const int buf = it & 1;
        bf16x8 af[4], bfv[4];
#pragma unroll
        for (int mi = 0; mi < 4; ++mi)
            af[mi] = *(const bf16x8*)(smem + buf * 4096 + l4 * 1024 +
                                      (((mi * 16 + l15) ^ (l4 << 2))) * 16);
#pragma unroll
        for (int nj = 0; nj < 4; ++nj)
            bfv[nj] = *(const bf16x8*)(bp + (long)it * 16384 + nj * 256);
#pragma unroll
        for (int mi = 0; mi < 4; ++mi)
#pragma unroll
            for (int nj = 0; nj < 4; ++nj)
                acc[mi][nj] = __builtin_amdgcn_mfma_f32_16x16x32_bf16(
                    af[mi], bfv[nj], acc[mi][nj], 0, 0, 0);
    }
#undef WRITE_NA8

    const int nb = wv * 64;
    float bs[4];
#pragma unroll
    for (int nj = 0; nj < 4; ++nj) bs[nj] = bias[nb + nj * 16 + l15];
#pragma unroll
    for (int mi = 0; mi < 4; ++mi) {
#pragma unroll
        for (int r = 0; r < 4; ++r) {
            long gm = m0 + mi * 16 + l4 * 4 + r;
            if (gm < M) {
#pragma unroll
                for (int nj = 0; nj < 4; ++nj)
                    Y[gm * 256 + nb + nj * 16 + l15] = f2bf(acc[mi][nj][r] + bs[nj]);
            }
        }
    }
}

// ---------------------------------------------------------------------------
// Message+reduce, N=256 (gather via eidS; register run-accumulation).
// ---------------------------------------------------------------------------
__global__ __launch_bounds__(256) void msg256(
    const unsigned short* __restrict__ EAr, const unsigned short* __restrict__ XT,
    const int* __restrict__ rowS, const int* __restrict__ colS,
    const int* __restrict__ eidS, float* __restrict__ AGG, int E) {
    __shared__ __align__(16) unsigned short eas[64][264];
    __shared__ int rows_s[64];
    __shared__ int cols_s[64];
    const int tid = threadIdx.x;
    const long m0 = (long)blockIdx.x * 64;

    const int r = tid >> 2, s = tid & 3;
    {
        long p = m0 + r;
        if (p < E) {
            const unsigned short* src = EAr + (long)eidS[p] * 256 + s * 8;
#pragma unroll
            for (int k = 0; k < 8; ++k)
                *(u16x8*)&eas[r][s * 8 + k * 32] = *(const u16x8*)(src + k * 32);
        } else {
            u16x8 z = {};
#pragma unroll
            for (int k = 0; k < 8; ++k) *(u16x8*)&eas[r][s * 8 + k * 32] = z;
        }
    }
    if (tid < 64) {
        long p = m0 + tid;
        cols_s[tid] = (p < E) ? colS[p] : -1;
        rows_s[tid] = (p < E) ? rowS[p] : 0;
    }
    __syncthreads();

    const int c = tid;
    float sum = 0.f;
    int cur = cols_s[0];
    int runstart = 0;
#pragma unroll 1
    for (int g = 0; g < 8; ++g) {
        float xv[8];
#pragma unroll
        for (int j = 0; j < 8; ++j)
            xv[j] = bf2f(XT[(long)rows_s[g * 8 + j] * 256 + c]);
#pragma unroll
        for (int j = 0; j < 8; ++j) {
            int e = g * 8 + j;
            int cc = cols_s[e];
            if (cc != cur) {
                if (cur >= 0) {
                    float* dst = AGG + (long)cur * 256 + c;
                    if (runstart > 0) *dst = sum;
                    else atomicAdd(dst, sum);
                }
                cur = cc; runstart = e; sum = 0.f;
            }
            sum += bf2f(eas[e][c]) * xv[j];
        }
    }
    if (cur >= 0) {
        atomicAdd(AGG + (long)cur * 256 + c, sum);
    }
}

// ---------------------------------------------------------------------------
// Message+reduce, N=32 (output layer).
// ---------------------------------------------------------------------------
__global__ __launch_bounds__(256) void msg32(
    const unsigned short* __restrict__ EAro, const unsigned short* __restrict__ XT,
    const int* __restrict__ rowS, const int* __restrict__ colS,
    const int* __restrict__ eidS, float* __restrict__ AGG, int E) {
    __shared__ __align__(16) unsigned short eas[256][36];
    __shared__ int rows_s[256];
    __shared__ int cols_s[256];
    __shared__ int eid_s[256];
    const int tid = threadIdx.x;
    const long m0 = (long)blockIdx.x * 256;

    {
        long p = m0 + tid;
        cols_s[tid] = (p < E) ? colS[p] : -1;
        rows_s[tid] = (p < E) ? rowS[p] : 0;
        eid_s[tid]  = (p < E) ? eidS[p] : -1;
    }
    __syncthreads();
    const int rr0 = tid >> 2, s = tid & 3;
#pragma unroll
    for (int ps = 0; ps < 4; ++ps) {
        int rr = ps * 64 + rr0;
        int eid = eid_s[rr];
        u16x8 v = {};
        if (eid >= 0) v = *(const u16x8*)(EAro + (long)eid * 32 + s * 8);
        *(u16x8*)&eas[rr][s * 8] = v;
    }
    __syncthreads();

    const int c = tid & 31, sb = tid >> 5;
    const int e0 = sb * 32;
    float sum = 0.f;
    int cur = cols_s[e0];
    int runstart = e0;
#pragma unroll 1
    for (int g = 0; g < 4; ++g) {
        float xv[8];
#pragma unroll
        for (int j = 0; j < 8; ++j)
            xv[j] = bf2f(XT[(long)rows_s[e0 + g * 8 + j] * 32 + c]);
#pragma unroll
        for (int j = 0; j < 8; ++j) {
            int e = e0 + g * 8 + j;
            int cc = cols_s[e];
            if (cc != cur) {
                if (cur >= 0) {
                    float* dst = AGG + (long)cur * 32 + c;
                    if (runstart > 0 && cols_s[runstart - 1] != cur) *dst = sum;
                    else atomicAdd(dst, sum);
                }
                cur = cc; runstart = e; sum = 0.f;
            }
            sum += bf2f(eas[e][c]) * xv[j];
        }
    }
    if (cur >= 0) {
        int eend = e0 + 32;
        float* dst = AGG + (long)cur * 32 + c;
        bool oks = (runstart > 0 && cols_s[runstart - 1] != cur);
        bool oke = (eend < 256 && cols_s[eend] != cur);
        if (oks && oke) *dst = sum;
        else atomicAdd(dst, sum);
    }
}

// ---------------------------------------------------------------------------
// Node GEMM for concat input, N=32.
// ---------------------------------------------------------------------------
__global__ __launch_bounds__(256) void node_cat_mfma(
    const float* __restrict__ X, const float* __restrict__ H0,
    const float* __restrict__ H1, const unsigned short* __restrict__ Wh,
    const float* __restrict__ bias, unsigned short* __restrict__ Y, int M) {
    __shared__ __align__(16) unsigned short As[4][256][8];
    __shared__ __align__(16) unsigned short Bs[4][32][8];
    const int tid = threadIdx.x;
    const int wv = tid >> 6, lane = tid & 63;
    const int l15 = lane & 15, l4 = lane >> 4;
    const long m0 = (long)blockIdx.x * 256;
    f32x4 acc[4][2] = {};

    const int sr = tid >> 3;
    const int sq = (tid & 7) * 4;
    const int sg2 = sq >> 3, so2 = sq & 7;

    for (int it = 0; it < 24; ++it) {
        const int k0 = it * 32;
        const float* src = (it < 8) ? X : (it < 16) ? H0 : H1;
        const int kk = k0 & 255;
        float4 va[8];
#pragma unroll
        for (int j = 0; j < 8; ++j) {
            long r_ = m0 + j * 32 + sr;
            va[j] = (r_ < M) ? *(const float4*)(src + r_ * 256 + kk + sq)
                             : make_float4(0.f, 0.f, 0.f, 0.f);
        }
        u16x8 bv = {};
        if (tid < 128)
            bv = *(const u16x8*)(Wh + (long)(tid >> 2) * 768 + k0 + (tid & 3) * 8);
        __syncthreads();
#pragma unroll
        for (int j = 0; j < 8; ++j) {
            u16x4 ap;
            ap[0] = f2bf(va[j].x); ap[1] = f2bf(va[j].y);
            ap[2] = f2bf(va[j].z); ap[3] = f2bf(va[j].w);
            *(u16x4*)&As[sg2][j * 32 + sr][so2] = ap;
        }
        if (tid < 128) *(u16x8*)&Bs[tid & 3][tid >> 2][0] = bv;
        __syncthreads();
        bf16x8 af[4], bfv[2];
#pragma unroll
        for (int mi = 0; mi < 4; ++mi)
            af[mi] = *(const bf16x8*)&As[l4][wv * 64 + mi * 16 + l15][0];
#pragma unroll
        for (int nj = 0; nj < 2; ++nj)
            bfv[nj] = *(const bf16x8*)&Bs[l4][nj * 16 + l15][0];
#pragma unroll
        for (int mi = 0; mi < 4; ++mi)
#pragma unroll
            for (int nj = 0; nj < 2; ++nj)
                acc[mi][nj] = __builtin_amdgcn_mfma_f32_16x16x32_bf16(
                    af[mi], bfv[nj], acc[mi][nj], 0, 0, 0);
    }

#pragma unroll
    for (int mi = 0; mi < 4; ++mi) {
#pragma unroll
        for (int r = 0; r < 4; ++r) {
            long gm = m0 + wv * 64 + mi * 16 + l4 * 4 + r;
            if (gm < M) {
#pragma unroll
                for (int nj = 0; nj < 2; ++nj) {
                    int o = nj * 16 + l15;
                    Y[gm * 32 + o] = f2bf(acc[mi][nj][r] + bias[o]);
                }
            }
        }
    }
}

// ---------------------------------------------------------------------------
// Small f32 KAN for output layer (M x 32 -> M x 32).
// ---------------------------------------------------------------------------
__global__ __launch_bounds__(256) void kan_gemm32(
    const float* __restrict__ AGG, const float* __restrict__ Wc,
    float* __restrict__ Y, int M) {
    __shared__ float As[64][36];
    __shared__ float Bs[32][36];
    const int tid = threadIdx.x;
    const int tx = tid & 15, ty = tid >> 4;
    const int m0 = blockIdx.x * 64;
    float acc[4][2] = {{0.f, 0.f}, {0.f, 0.f}, {0.f, 0.f}, {0.f, 0.f}};
    const int er = tid >> 2, ef = tid & 3;
    const int em = m0 + er;
    for (int ic = 0; ic < 32; ic += 4) {
        float xv = (em < M) ? AGG[(long)em * 32 + ic + ef] : 0.f;
        float e8[8];
        expand8(xv, e8);
        *(float4*)&As[er][ef * 8] = make_float4(e8[0], e8[1], e8[2], e8[3]);
        *(float4*)&As[er][ef * 8 + 4] = make_float4(e8[4], e8[5], e8[6], e8[7]);
        {
            int o = tid >> 3, k4 = (tid & 7) * 4;
            *(float4*)&Bs[o][k4] = *(const float4*)&Wc[(long)o * 256 + ic * 8 + k4];
        }
        __syncthreads();
#pragma unroll
        for (int kk = 0; kk < 32; ++kk) {
            float a_[4], b_[2];
#pragma unroll
            for (int i = 0; i < 4; ++i) a_[i] = As[ty * 4 + i][kk];
#pragma unroll
            for (int j = 0; j < 2; ++j) b_[j] = Bs[tx * 2 + j][kk];
#pragma unroll
            for (int i = 0; i < 4; ++i)
#pragma unroll
                for (int j = 0; j < 2; ++j) acc[i][j] = fmaf(a_[i], b_[j], acc[i][j]);
        }
        __syncthreads();
    }
#pragma unroll
    for (int i = 0; i < 4; ++i) {
        int gm = m0 + ty * 4 + i;
        if (gm >= M) continue;
#pragma unroll
        for (int j = 0; j < 2; ++j) Y[(long)gm * 32 + tx * 2 + j] = acc[i][j];
    }
}

// ---------------------------------------------------------------------------
// Misc weight prep
// ---------------------------------------------------------------------------
__global__ __launch_bounds__(256) void cvt_bf16(
    const float* __restrict__ s, unsigned short* __restrict__ d, int n) {
    int i = blockIdx.x * 256 + threadIdx.x;
    if (i < n) d[i] = f2bf(s[i]);
}

__global__ __launch_bounds__(256) void pack_kan_f32(
    const float* __restrict__ baseW, const float* __restrict__ splineW,
    float* __restrict__ Wc, int n) {
    int idx = blockIdx.x * 256 + threadIdx.x;
    if (idx >= n) return;
    float* dst = Wc + (long)idx * 8;
    dst[0] = baseW[idx];
    const float* sw = splineW + (long)idx * 7;
#pragma unroll
    for (int c = 0; c < 7; ++c) dst[1 + c] = sw[c];
}

// ---------------------------------------------------------------------------
extern "C" void kernel_launch(void* const* d_in, const int* in_sizes, int n_in,
                              void* d_out, int out_size, void* d_ws, size_t ws_size,
                              hipStream_t stream) {
    const float* x          = (const float*)d_in[0];
    const int*   edge_index = (const int*)d_in[1];
    const float* edge_attr  = (const float*)d_in[2];
    const float* node_W0 = (const float*)d_in[3];
    const float* node_b0 = (const float*)d_in[4];
    const float* edge_W0 = (const float*)d_in[5];
    const float* edge_b0 = (const float*)d_in[6];
    const float* base_W0 = (const float*)d_in[7];
    const float* spline_W0 = (const float*)d_in[8];
    const float* node_W1 = (const float*)d_in[9];
    const float* node_b1 = (const float*)d_in[10];
    const float* edge_W1 = (const float*)d_in[11];
    const float* edge_b1 = (const float*)d_in[12];
    const float* base_W1 = (const float*)d_in[13];
    const float* spline_W1 = (const float*)d_in[14];
    const float* node_Wo = (const float*)d_in[15];
    const float* node_bo = (const float*)d_in[16];
    const float* edge_Wo = (const float*)d_in[17];
    const float* edge_bo = (const float*)d_in[18];
    const float* base_Wo = (const float*)d_in[19];
    const float* spline_Wo = (const float*)d_in[20];
    float* out = (float*)d_out;

    const int N = in_sizes[0] / 256;
    const int E = in_sizes[1] / 2;

    float* ws  = (float*)d_ws;
    unsigned short* xt = (unsigned short*)ws;  // bf16 XT (slot sized N*256 f32)
    float* agg = ws + (long)N * 256;           // N*256 f32
    float* h0  = agg + (long)N * 256;
    float* h1  = h0 + (long)N * 256;
    float* Wco = h1 + (long)N * 256;           // 32*256 f32
    unsigned short* Wp0  = (unsigned short*)(Wco + 32 * 256);  // 98304
    unsigned short* Wp1  = Wp0 + 98304;
    unsigned short* Wpo  = Wp1 + 98304;                        // 12288
    unsigned short* nWp0 = Wpo + 12288;                        // 65536
    unsigned short* nWp1 = nWp0 + 65536;
    unsigned short* Wc0p = nWp1 + 65536;                       // 524288
    unsigned short* Wc1p = Wc0p + 524288;
    unsigned short* nWoh = Wc1p + 524288;                      // 24576
    int* cursor = (int*)(nWoh + 24576);
    int* rowS   = cursor + (N + 1);
    int* colS   = rowS + E;
    int* eidS   = colS + E;
    unsigned short* EAr0 = (unsigned short*)(((uintptr_t)(eidS + E) + 255) & ~(uintptr_t)255);
    const int nt256 = (E + 255) / 256;
    const long Epad = (long)nt256 * 256;
    unsigned short* EAr1 = EAr0 + Epad * 256;

    const size_t need2 = (size_t)((char*)(EAr1 + Epad * 256 + Epad * 32) - (char*)d_ws);
    const bool two = ws_size >= need2;
    unsigned short* EAro = two ? (EAr1 + Epad * 256) : (EAr0 + Epad * 256);

    const int* row = edge_index;
    const int* col = edge_index + E;

    const int nb64 = (N + 63) / 64;
    const int eb64 = (E + 63) / 64;
    const int eb256 = (E + 255) / 256;
    const int nb256 = (N + 255) / 256;

    // ---- counting sort of edges by destination ----
    hipMemsetAsync(cursor, 0, (size_t)(N + 1) * sizeof(int), stream);
    k_hist<<<eb256, 256, 0, stream>>>(col, cursor, E);
    k_scan<<<1, 1024, 0, stream>>>(cursor, N);
    k_scatter<<<eb256, 256, 0, stream>>>(row, col, cursor, rowS, colS, eidS, E);

    // ---- weight prep: K-step-tiled packs ----
    pack_kt<<<(256 * 384 + 255) / 256, 256, 0, stream>>>(edge_W0, Wp0, 256, 384);
    pack_kt<<<(256 * 384 + 255) / 256, 256, 0, stream>>>(edge_W1, Wp1, 256, 384);
    pack_kt<<<(32 * 384 + 255) / 256, 256, 0, stream>>>(edge_Wo, Wpo, 32, 384);
    pack_kt<<<(256 * 256 + 255) / 256, 256, 0, stream>>>(node_W0, nWp0, 256, 256);
    pack_kt<<<(256 * 256 + 255) / 256, 256, 0, stream>>>(node_W1, nWp1, 256, 256);
    pack_kan_kt<<<(256 * 2048 + 255) / 256, 256, 0, stream>>>(base_W0, spline_W0, Wc0p, 256);
    pack_kan_kt<<<(256 * 2048 + 255) / 256, 256, 0, stream>>>(base_W1, spline_W1, Wc1p, 256);
    cvt_bf16<<<(32 * 768 + 255) / 256, 256, 0, stream>>>(node_Wo, nWoh, 32 * 768);
    pack_kan_f32<<<(32 * 32 + 255) / 256, 256, 0, stream>>>(base_Wo, spline_Wo, Wco, 32 * 32);

    // ---- edge GEMMs (8-wave blocks, B direct-to-register) ----
    if (two) {
        ea_gemm9<true, true><<<eb64, 512, 0, stream>>>(
            edge_attr, Wp0, edge_b0, Wp1, edge_b1, Wpo, edge_bo,
            EAr0, EAr1, EAro, E);
    } else {
        ea_gemm9<false, true><<<eb64, 512, 0, stream>>>(
            edge_attr, Wp0, edge_b0, Wp0, edge_b0, Wpo, edge_bo,
            EAr0, EAr0, EAro, E);
    }

    // ---- layer 0 ----
    hipMemsetAsync(agg, 0, (size_t)N * 256 * sizeof(float), stream);
    node_mfma_r<256><<<nb64, 256, 0, stream>>>(x, nWp0, node_b0, xt, N);
    msg256<<<eb64, 256, 0, stream>>>(EAr0, xt, rowS, colS, eidS, agg, E);
    kan_mfma256_r<<<nb64, 256, 0, stream>>>(agg, Wc0p, h0, N);

    // ---- layer 1 ----
    if (!two) {
        ea_gemm9<false, false><<<eb64, 512, 0, stream>>>(
            edge_attr, Wp1, edge_b1, Wp1, edge_b1, Wpo, edge_bo,
            EAr0, EAr0, EAro, E);
    }
    hipMemsetAsync(agg, 0, (size_t)N * 256 * sizeof(float), stream);
    node_mfma_r<256><<<nb64, 256, 0, stream>>>(h0, nWp1, node_b1, xt, N);
    msg256<<<eb64, 256, 0, stream>>>(two ? EAr1 : EAr0, xt, rowS, colS, eidS, agg, E);
    kan_mfma256_r<<<nb64, 256, 0, stream>>>(agg, Wc1p, h1, N);

    // ---- output layer ----
    hipMemsetAsync(agg, 0, (size_t)N * 32 * sizeof(float), stream);
    node_cat_mfma<<<nb256, 256, 0, stream>>>(x, h0, h1, nWoh, node_bo, xt, N);
    msg32<<<eb256, 256, 0, stream>>>(EAro, xt, rowS, colS, eidS, agg, E);
    kan_gemm32<<<nb64, 256, 0, stream>>>(agg, Wco, out, N);
}

// Round 14
// 1318.224 us; speedup vs baseline: 1.0964x; 1.0767x over previous
//
#include <hip/hip_runtime.h>

// ---------------------------------------------------------------------------
// GCKAN (3 layers) on MI355X — round 16: REVERT to round-12 (session-best
// 1319us) configuration. ea_gemm7: 2-blocks/CU merged edge GEMM, counted
// vmcnt(2) entry waits, depth-2 A register pipeline, packed fragment-native
// weights; kan/node GEMMs with dense gl16 packed-B staging; msg kernels
// gather sorted tiles via eidS. The 8-wave direction (rounds 14/15)
// regressed (spills / allocator serialization) and is abandoned.
// ---------------------------------------------------------------------------

typedef __attribute__((ext_vector_type(4))) float f32x4;
typedef __attribute__((ext_vector_type(8))) short bf16x8;
typedef __attribute__((ext_vector_type(8))) unsigned short u16x8;
typedef __attribute__((ext_vector_type(4))) unsigned short u16x4;

__device__ __forceinline__ unsigned short f2bf(float f) {
    union { float f; unsigned u; } v; v.f = f;
    unsigned r = v.u + 0x7FFFu + ((v.u >> 16) & 1u);
    return (unsigned short)(r >> 16);
}

__device__ __forceinline__ float bf2f(unsigned short u) {
    union { unsigned u; float f; } v; v.u = ((unsigned)u) << 16;
    return v.f;
}

__device__ __forceinline__ float siluf(float x) {
    return x / (1.0f + __expf(-x));
}

// async global->LDS, 16B per lane; LDS dest wave-uniform (HW adds lane*16).
__device__ __forceinline__ void gl16(const void* g, void* l) {
    __builtin_amdgcn_global_load_lds(
        (const __attribute__((address_space(1))) unsigned*)g,
        (__attribute__((address_space(3))) unsigned*)l, 16, 0, 0);
}

// Expand scalar x -> 8 channels [silu, B0..B6]; cubic B-spline on uniform
// knots t_i = 0.5 i - 2.5 (matches reference Cox-de Boor exactly).
__device__ __forceinline__ void expand8(float x, float* o8) {
    float b[10];
#pragma unroll
    for (int i = 0; i < 10; ++i) {
        float ti = 0.5f * i - 2.5f;
        b[i] = (x >= ti && x < ti + 0.5f) ? 1.0f : 0.0f;
    }
#pragma unroll
    for (int j = 1; j <= 3; ++j) {
        float inv = 2.0f / (float)j;
#pragma unroll
        for (int i = 0; i < 10 - j; ++i) {
            float ti = 0.5f * i - 2.5f;
            float tj = 0.5f * (i + j + 1) - 2.5f;
            b[i] = (x - ti) * inv * b[i] + (tj - x) * inv * b[i + 1];
        }
    }
    o8[0] = siluf(x);
#pragma unroll
    for (int c = 0; c < 7; ++c) o8[c + 1] = b[c];
}

// ---------------------------------------------------------------------------
// Edge counting sort by destination (col).
// ---------------------------------------------------------------------------
__global__ __launch_bounds__(256) void k_hist(
    const int* __restrict__ col, int* __restrict__ cnt, int E) {
    int i = blockIdx.x * 256 + threadIdx.x;
    if (i < E) atomicAdd(&cnt[col[i]], 1);
}

__global__ __launch_bounds__(1024) void k_scan(int* __restrict__ c, int N) {
    __shared__ int wsum[16];
    __shared__ int ctot;
    const int t = threadIdx.x;
    const int lane = t & 63, wid = t >> 6;
    int carry = 0;
    for (int base = 0; base < N; base += 1024) {
        int i = base + t;
        int v0 = (i < N) ? c[i] : 0;
        int v = v0;
#pragma unroll
        for (int off = 1; off < 64; off <<= 1) {
            int n = __shfl_up(v, (unsigned)off, 64);
            if (lane >= off) v += n;
        }
        if (lane == 63) wsum[wid] = v;
        __syncthreads();
        if (t < 16) {
            int s = wsum[t], sv = s;
#pragma unroll
            for (int off = 1; off < 16; off <<= 1) {
                int n = __shfl_up(sv, (unsigned)off, 16);
                if (t >= off) sv += n;
            }
            wsum[t] = sv - s;
            if (t == 15) ctot = sv;
        }
        __syncthreads();
        if (i < N) c[i] = carry + wsum[wid] + v - v0;
        carry += ctot;
        __syncthreads();
    }
}

__global__ __launch_bounds__(256) void k_scatter(
    const int* __restrict__ row, const int* __restrict__ col,
    int* __restrict__ cursor, int* __restrict__ rowS,
    int* __restrict__ colS, int* __restrict__ eidS, int E) {
    int i = blockIdx.x * 256 + threadIdx.x;
    if (i < E) {
        int c = col[i];
        int p = atomicAdd(&cursor[c], 1);
        rowS[p] = row[i];
        colS[p] = c;
        eidS[p] = i;
    }
}

// ---------------------------------------------------------------------------
// Weight prep: pack [N][K] f32 -> K-step-tiled bf16:
//   dst[(( (k>>5)*4 + ((k>>3)&3) )*N + n)*8 + (k&7)]
// ---------------------------------------------------------------------------
__global__ __launch_bounds__(256) void pack_kt(
    const float* __restrict__ src, unsigned short* __restrict__ dst,
    int N, int K) {
    long idx = (long)blockIdx.x * 256 + threadIdx.x;
    if (idx >= (long)N * K) return;
    int n = (int)(idx / K), k = (int)(idx - (long)n * K);
    long o = (((long)(k >> 5) * 4 + ((k >> 3) & 3)) * N + n) * 8 + (k & 7);
    dst[o] = f2bf(src[idx]);
}

__global__ __launch_bounds__(256) void pack_kan_kt(
    const float* __restrict__ baseW, const float* __restrict__ splineW,
    unsigned short* __restrict__ dst, int N) {
    long idx = (long)blockIdx.x * 256 + threadIdx.x;   // n*2048 + k
    if (idx >= (long)N * 2048) return;
    int n = (int)(idx >> 11), k = (int)(idx & 2047);
    int ic = k >> 3, c = k & 7;
    float v = (c == 0) ? baseW[(long)n * 256 + ic]
                       : splineW[((long)n * 256 + ic) * 7 + (c - 1)];
    long o = (((long)(k >> 5) * 4 + ((k >> 3) & 3)) * N + n) * 8 + (k & 7);
    dst[o] = f2bf(v);
}

// ---------------------------------------------------------------------------
// ea_gemm7: 2-blocks/CU merged edge GEMM.
// Per-step issue order (fixed, sched_barrier-pinned):
//   [entry vmcnt(2) lgkm(0) barrier]
//   ISSUE_B(it+1)[8], ISSUE_WO(it+1)[wv>=2:1], WRITE_A(it+1)[ds],
//   A-load(it+3)[2], compute step it.
// Entry wait drains B(it)+WO(it)+A(it+1), keeps A(it+2) (the 2 newest).
// ---------------------------------------------------------------------------
template <bool TWO, bool WITH_O>
__global__ __launch_bounds__(256, 2) void ea_gemm7(
    const float* __restrict__ EA,
    const unsigned short* __restrict__ Wp0, const float* __restrict__ b0,
    const unsigned short* __restrict__ Wp1, const float* __restrict__ b1,
    const unsigned short* __restrict__ Wpo, const float* __restrict__ bo,
    unsigned short* __restrict__ O0, unsigned short* __restrict__ O1,
    unsigned short* __restrict__ Oo, int E) {
    constexpr int BSZ = TWO ? 32768 : 16384;      // one B buffer (1 or 2 panels)
    constexpr int WOOFF = 8192 + 2 * BSZ;         // A dbuf 8KB + B dbuf
    constexpr int SMEMSZ = WOOFF + (WITH_O ? 4096 : 0);   // + Wo dbuf 2x2KB
    __shared__ __align__(16) char smem[SMEMSZ];

    const int tid = threadIdx.x;
    const int wv = tid >> 6, lane = tid & 63;
    const int l15 = lane & 15, l4 = lane >> 4;
    const long m0 = (long)blockIdx.x * 64;

    f32x4 acc0[4][4] = {};
    f32x4 acc1[4][4] = {};
    f32x4 acco[4] = {};

    const int sr = tid >> 2, sg = tid & 3;
    const long arow = m0 + sr;
    const bool aok = arow < E;
    const float* aptr = EA + arow * 384 + sg * 8;
    const int awoff = sg * 1024 + ((sr ^ (sg << 2))) * 16;   // XOR-swizzled row

    const char* wp0 = (const char*)Wp0;
    const char* wp1 = (const char*)Wp1;
    const char* wpo = (const char*)Wpo;
    const int ci = lane * 16;

#define ISSUE_B7(IT, BUF)                                                      \
    {                                                                          \
        _Pragma("unroll")                                                      \
        for (int g = 0; g < 4; ++g) {                                          \
            int ch = g * 4 + wv;                                               \
            gl16(wp0 + (long)(IT) * 16384 + ch * 1024 + ci,                    \
                 smem + 8192 + (BUF) * BSZ + ch * 1024);                       \
        }                                                                      \
        if (TWO) {                                                             \
            _Pragma("unroll")                                                  \
            for (int g = 0; g < 4; ++g) {                                      \
                int ch = g * 4 + wv;                                           \
                gl16(wp1 + (long)(IT) * 16384 + ch * 1024 + ci,                \
                     smem + 8192 + (BUF) * BSZ + 16384 + ch * 1024);           \
            }                                                                  \
        }                                                                      \
        __builtin_amdgcn_sched_barrier(0);                                     \
    }

#define ISSUE_WO7(IT, BUF)                                                     \
    {                                                                          \
        if (WITH_O && wv >= 2)                                                 \
            gl16(wpo + (long)(IT) * 2048 + (wv - 2) * 1024 + ci,               \
                 smem + WOOFF + (BUF) * 2048 + (wv - 2) * 1024);               \
        __builtin_amdgcn_sched_barrier(0);                                     \
    }

#define WRITE_A7(IT, VA, VB)                                                   \
    {                                                                          \
        u16x8 rr = {};                                                         \
        if (aok) {                                                             \
            rr[0] = f2bf((VA).x); rr[1] = f2bf((VA).y);                        \
            rr[2] = f2bf((VA).z); rr[3] = f2bf((VA).w);                        \
            rr[4] = f2bf((VB).x); rr[5] = f2bf((VB).y);                        \
            rr[6] = f2bf((VB).z); rr[7] = f2bf((VB).w);                        \
        }                                                                      \
        *(u16x8*)(smem + ((IT) & 1) * 4096 + awoff) = rr;                      \
        __builtin_amdgcn_sched_barrier(0);                                     \
    }

    // ---- prologue ----
    const float4 z4 = make_float4(0.f, 0.f, 0.f, 0.f);
    {
        float4 s0 = z4, s1 = z4;
        if (aok) { s0 = *(const float4*)(aptr); s1 = *(const float4*)(aptr + 4); }
        WRITE_A7(0, s0, s1);          // synchronous; queue empty otherwise
    }
    float4 r1a = z4, r1b = z4, r0a = z4, r0b = z4;
    if (aok) { r1a = *(const float4*)(aptr + 32); r1b = *(const float4*)(aptr + 36); }
    __builtin_amdgcn_sched_barrier(0);
    ISSUE_B7(0, 0);
    ISSUE_WO7(0, 0);
    if (aok) { r0a = *(const float4*)(aptr + 64); r0b = *(const float4*)(aptr + 68); }
    __builtin_amdgcn_sched_barrier(0);
    // queue (oldest->newest): [load(1)^2, B(0), WO(0), load(2)^2]

#pragma unroll
    for (int it = 0; it < 12; ++it) {
        // entry wait: drain B(it)+WO(it)+A(it+1); keep A(it+2) (2 newest)
        if (it <= 9) asm volatile("s_waitcnt vmcnt(2)" ::: "memory");
        else         asm volatile("s_waitcnt vmcnt(0)" ::: "memory");
        asm volatile("s_waitcnt lgkmcnt(0)" ::: "memory");
        __builtin_amdgcn_s_barrier();
        __builtin_amdgcn_sched_barrier(0);

        if (it < 11) {
            const int nbf = (it + 1) & 1;
            ISSUE_B7(it + 1, nbf);
            ISSUE_WO7(it + 1, nbf);
            // WRITE_A(it+1) from the reg set filled 2 steps ago (drained)
            if ((it + 1) & 1) { WRITE_A7(it + 1, r1a, r1b); }
            else              { WRITE_A7(it + 1, r0a, r0b); }
            // issue load(it+3) into the set just consumed
            if (it <= 8) {
                if ((it + 3) & 1) {
                    if (aok) {
                        r1a = *(const float4*)(aptr + (it + 3) * 32);
                        r1b = *(const float4*)(aptr + (it + 3) * 32 + 4);
                    }
                } else {
                    if (aok) {
                        r0a = *(const float4*)(aptr + (it + 3) * 32);
                        r0b = *(const float4*)(aptr + (it + 3) * 32 + 4);
                    }
                }
                __builtin_amdgcn_sched_barrier(0);
            }
        }

        // ---- compute step it ----
        const int buf = it & 1;
        bf16x8 af[4];
#pragma unroll
        for (int mi = 0; mi < 4; ++mi)
            af[mi] = *(const bf16x8*)(smem + buf * 4096 + l4 * 1024 +
                                      (((mi * 16 + l15) ^ (l4 << 2))) * 16);
        {
            bf16x8 bf0[4];
#pragma unroll
            for (int nj = 0; nj < 4; ++nj)
                bf0[nj] = *(const bf16x8*)(smem + 8192 + buf * BSZ + l4 * 4096 +
                                           (wv * 64 + nj * 16 + l15) * 16);
#pragma unroll
            for (int mi = 0; mi < 4; ++mi)
#pragma unroll
                for (int nj = 0; nj < 4; ++nj)
                    acc0[mi][nj] = __builtin_amdgcn_mfma_f32_16x16x32_bf16(
                        af[mi], bf0[nj], acc0[mi][nj], 0, 0, 0);
        }
        if (TWO) {
            bf16x8 bf1[4];
#pragma unroll
            for (int nj = 0; nj < 4; ++nj)
                bf1[nj] = *(const bf16x8*)(smem + 8192 + buf * BSZ + 16384 +
                                           l4 * 4096 + (wv * 64 + nj * 16 + l15) * 16);
#pragma unroll
            for (int mi = 0; mi < 4; ++mi)
#pragma unroll
                for (int nj = 0; nj < 4; ++nj)
                    acc1[mi][nj] = __builtin_amdgcn_mfma_f32_16x16x32_bf16(
                        af[mi], bf1[nj], acc1[mi][nj], 0, 0, 0);
        }
        if (WITH_O && wv < 2) {
            bf16x8 bov = *(const bf16x8*)(smem + WOOFF + buf * 2048 + l4 * 512 +
                                          (wv * 16 + l15) * 16);
#pragma unroll
            for (int mi = 0; mi < 4; ++mi)
                acco[mi] = __builtin_amdgcn_mfma_f32_16x16x32_bf16(
                    af[mi], bov, acco[mi], 0, 0, 0);
        }
    }
#undef ISSUE_B7
#undef ISSUE_WO7
#undef WRITE_A7

    // ---- epilogue: bias + bf16 store, original order (linear) ----
    const int nb2 = wv * 64;
    float bs0[4];
#pragma unroll
    for (int nj = 0; nj < 4; ++nj) bs0[nj] = b0[nb2 + nj * 16 + l15];
#pragma unroll
    for (int mi = 0; mi < 4; ++mi) {
#pragma unroll
        for (int r = 0; r < 4; ++r) {
            long e = m0 + mi * 16 + l4 * 4 + r;
            if (e < E) {
                unsigned short* dst = O0 + e * 256 + nb2 + l15;
#pragma unroll
                for (int nj = 0; nj < 4; ++nj)
                    dst[nj * 16] = f2bf(acc0[mi][nj][r] + bs0[nj]);
            }
        }
    }
    if (TWO) {
        float bs1[4];
#pragma unroll
        for (int nj = 0; nj < 4; ++nj) bs1[nj] = b1[nb2 + nj * 16 + l15];
#pragma unroll
        for (int mi = 0; mi < 4; ++mi) {
#pragma unroll
            for (int r = 0; r < 4; ++r) {
                long e = m0 + mi * 16 + l4 * 4 + r;
                if (e < E) {
                    unsigned short* dst = O1 + e * 256 + nb2 + l15;
#pragma unroll
                    for (int nj = 0; nj < 4; ++nj)
                        dst[nj * 16] = f2bf(acc1[mi][nj][r] + bs1[nj]);
                }
            }
        }
    }
    if (WITH_O && wv < 2) {
        float bso = bo[wv * 16 + l15];
#pragma unroll
        for (int mi = 0; mi < 4; ++mi) {
#pragma unroll
            for (int r = 0; r < 4; ++r) {
                long e = m0 + mi * 16 + l4 * 4 + r;
                if (e < E)
                    Oo[e * 32 + wv * 16 + l15] = f2bf(acco[mi][r] + bso);
            }
        }
    }
}

// ---------------------------------------------------------------------------
// KAN linear N=256, PACKED weights (counted vmcnt, dense gl16 B staging).
// ---------------------------------------------------------------------------
__global__ __launch_bounds__(256) void kan_mfma256_p(
    const float* __restrict__ AGG, const unsigned short* __restrict__ Wp,
    float* __restrict__ Y, int M) {
    __shared__ __align__(16) char smem[8192 + 2 * 16384];
    const int tid = threadIdx.x;
    const int wv = tid >> 6, lane = tid & 63;
    const int l15 = lane & 15, l4 = lane >> 4;
    const long m0 = (long)blockIdx.x * 64;
    f32x4 acc[4][4] = {};

    const int srow = tid & 63, sg = tid >> 6;
    const long arow = m0 + srow;
    const bool aok = arow < M;
    const float* aptr = AGG + arow * 256 + sg;
    const char* wp = (const char*)Wp;
    const int ci = lane * 16;
    const int awoff = sg * 1024 + srow * 16;

#define ISSUE_KB(IT, BUF)                                                      \
    {                                                                          \
        _Pragma("unroll")                                                      \
        for (int g = 0; g < 4; ++g) {                                          \
            int ch = g * 4 + wv;                                               \
            gl16(wp + (long)(IT) * 16384 + ch * 1024 + ci,                     \
                 smem + 8192 + (BUF) * 16384 + ch * 1024);                     \
        }                                                                      \
        __builtin_amdgcn_sched_barrier(0);                                     \
    }

    float xv0 = aok ? aptr[0] : 0.f;
    ISSUE_KB(0, 0);
    {
        float e8[8];
        expand8(xv0, e8);
        u16x8 ap;
#pragma unroll
        for (int c = 0; c < 8; ++c) ap[c] = f2bf(e8[c]);
        *(u16x8*)(smem + awoff) = ap;
    }
    float xv1 = aok ? aptr[4] : 0.f;
    __builtin_amdgcn_sched_barrier(0);

    for (int it = 0; it < 64; ++it) {
        if (it == 63) asm volatile("s_waitcnt vmcnt(0)" ::: "memory");
        else          asm volatile("s_waitcnt vmcnt(1)" ::: "memory");
        asm volatile("s_waitcnt lgkmcnt(0)" ::: "memory");
        __builtin_amdgcn_s_barrier();
        __builtin_amdgcn_sched_barrier(0);
        const int buf = it & 1, nbf = buf ^ 1;
        if (it < 63) {
            ISSUE_KB(it + 1, nbf);
            {
                float e8[8];
                expand8(xv1, e8);
                u16x8 ap;
#pragma unroll
                for (int c = 0; c < 8; ++c) ap[c] = f2bf(e8[c]);
                *(u16x8*)(smem + nbf * 4096 + awoff) = ap;
            }
            __builtin_amdgcn_sched_barrier(0);
            if (it < 62) {
                xv1 = aok ? aptr[(it + 2) * 4] : 0.f;
                __builtin_amdgcn_sched_barrier(0);
            }
        }
        bf16x8 af[4], bfv[4];
#pragma unroll
        for (int mi = 0; mi < 4; ++mi)
            af[mi] = *(const bf16x8*)(smem + buf * 4096 + l4 * 1024 +
                                      (mi * 16 + l15) * 16);
#pragma unroll
        for (int nj = 0; nj < 4; ++nj)
            bfv[nj] = *(const bf16x8*)(smem + 8192 + buf * 16384 + l4 * 4096 +
                                       (wv * 64 + nj * 16 + l15) * 16);
#pragma unroll
        for (int mi = 0; mi < 4; ++mi)
#pragma unroll
            for (int nj = 0; nj < 4; ++nj)
                acc[mi][nj] = __builtin_amdgcn_mfma_f32_16x16x32_bf16(
                    af[mi], bfv[nj], acc[mi][nj], 0, 0, 0);
    }
#undef ISSUE_KB

    const int nb = wv * 64;
#pragma unroll
    for (int mi = 0; mi < 4; ++mi) {
#pragma unroll
        for (int r = 0; r < 4; ++r) {
            long gm = m0 + mi * 16 + l4 * 4 + r;
            if (gm < M) {
#pragma unroll
                for (int nj = 0; nj < 4; ++nj)
                    Y[gm * 256 + nb + nj * 16 + l15] = acc[mi][nj][r];
            }
        }
    }
}

// ---------------------------------------------------------------------------
// Node GEMM N=256, PACKED weights.
// ---------------------------------------------------------------------------
template <int K>
__global__ __launch_bounds__(256) void node_mfma_p(
    const float* __restrict__ X, const unsigned short* __restrict__ Wp,
    const float* __restrict__ bias, unsigned short* __restrict__ Y, int M) {
    __shared__ __align__(16) char smem[8192 + 2 * 16384];
    const int tid = threadIdx.x;
    const int wv = tid >> 6, lane = tid & 63;
    const int l15 = lane & 15, l4 = lane >> 4;
    const long m0 = (long)blockIdx.x * 64;
    f32x4 acc[4][4] = {};
    constexpr int NIT = K / 32;

    const int sr = tid >> 2, sg = tid & 3;
    const long arow = m0 + sr;
    const bool aok = arow < M;
    const float* aptr = X + arow * K + sg * 8;
    const int awoff = sg * 1024 + ((sr ^ (sg << 2))) * 16;
    const char* wp = (const char*)Wp;
    const int ci = lane * 16;

#define ISSUE_NB(IT, BUF)                                                      \
    {                                                                          \
        _Pragma("unroll")                                                      \
        for (int g = 0; g < 4; ++g) {                                          \
            int ch = g * 4 + wv;                                               \
            gl16(wp + (long)(IT) * 16384 + ch * 1024 + ci,                     \
                 smem + 8192 + (BUF) * 16384 + ch * 1024);                     \
        }                                                                      \
        __builtin_amdgcn_sched_barrier(0);                                     \
    }

#define WRITE_NA(BUF)                                                          \
    {                                                                          \
        u16x8 rr = {};                                                         \
        if (aok) {                                                             \
            rr[0] = f2bf(a0v.x); rr[1] = f2bf(a0v.y);                          \
            rr[2] = f2bf(a0v.z); rr[3] = f2bf(a0v.w);                          \
            rr[4] = f2bf(a1v.x); rr[5] = f2bf(a1v.y);                          \
            rr[6] = f2bf(a1v.z); rr[7] = f2bf(a1v.w);                          \
        }                                                                      \
        *(u16x8*)(smem + (BUF) * 4096 + awoff) = rr;                           \
        __builtin_amdgcn_sched_barrier(0);                                     \
    }

    ISSUE_NB(0, 0);
    float4 a0v = make_float4(0.f, 0.f, 0.f, 0.f);
    float4 a1v = make_float4(0.f, 0.f, 0.f, 0.f);
    if (aok) { a0v = *(const float4*)(aptr); a1v = *(const float4*)(aptr + 4); }
    WRITE_NA(0);
    if (aok) { a0v = *(const float4*)(aptr + 32); a1v = *(const float4*)(aptr + 36); }
    __builtin_amdgcn_sched_barrier(0);

#pragma unroll
    for (int it = 0; it < NIT; ++it) {
        if (it == NIT - 1) asm volatile("s_waitcnt vmcnt(0)" ::: "memory");
        else               asm volatile("s_waitcnt vmcnt(2)" ::: "memory");
        asm volatile("s_waitcnt lgkmcnt(0)" ::: "memory");
        __builtin_amdgcn_s_barrier();
        __builtin_amdgcn_sched_barrier(0);
        const int buf = it & 1, nbf = buf ^ 1;
        if (it < NIT - 1) {
            ISSUE_NB(it + 1, nbf);
            WRITE_NA(nbf);
            if (it < NIT - 2) {
                if (aok) {
                    a0v = *(const float4*)(aptr + (it + 2) * 32);
                    a1v = *(const float4*)(aptr + (it + 2) * 32 + 4);
                }
                __builtin_amdgcn_sched_barrier(0);
            }
        }
        bf16x8 af[4], bfv[4];
#pragma unroll
        for (int mi = 0; mi < 4; ++mi)
            af[mi] = *(const bf16x8*)(smem + buf * 4096 + l4 * 1024 +
                                      (((mi * 16 + l15) ^ (l4 << 2))) * 16);
#pragma unroll
        for (int nj = 0; nj < 4; ++nj)
            bfv[nj] = *(const bf16x8*)(smem + 8192 + buf * 16384 + l4 * 4096 +
                                       (wv * 64 + nj * 16 + l15) * 16);
#pragma unroll
        for (int mi = 0; mi < 4; ++mi)
#pragma unroll
            for (int nj = 0; nj < 4; ++nj)
                acc[mi][nj] = __builtin_amdgcn_mfma_f32_16x16x32_bf16(
                    af[mi], bfv[nj], acc[mi][nj], 0, 0, 0);
    }
#undef ISSUE_NB
#undef WRITE_NA

    const int nb = wv * 64;
    float bs[4];
#pragma unroll
    for (int nj = 0; nj < 4; ++nj) bs[nj] = bias[nb + nj * 16 + l15];
#pragma unroll
    for (int mi = 0; mi < 4; ++mi) {
#pragma unroll
        for (int r = 0; r < 4; ++r) {
            long gm = m0 + mi * 16 + l4 * 4 + r;
            if (gm < M) {
#pragma unroll
                for (int nj = 0; nj < 4; ++nj)
                    Y[gm * 256 + nb + nj * 16 + l15] = f2bf(acc[mi][nj][r] + bs[nj]);
            }
        }
    }
}

// ---------------------------------------------------------------------------
// Message+reduce, N=256 (gather via eidS; register run-accumulation).
// ---------------------------------------------------------------------------
__global__ __launch_bounds__(256) void msg256(
    const unsigned short* __restrict__ EAr, const unsigned short* __restrict__ XT,
    const int* __restrict__ rowS, const int* __restrict__ colS,
    const int* __restrict__ eidS, float* __restrict__ AGG, int E) {
    __shared__ __align__(16) unsigned short eas[64][264];
    __shared__ int rows_s[64];
    __shared__ int cols_s[64];
    const int tid = threadIdx.x;
    const long m0 = (long)blockIdx.x * 64;

    const int r = tid >> 2, s = tid & 3;
    {
        long p = m0 + r;
        if (p < E) {
            const unsigned short* src = EAr + (long)eidS[p] * 256 + s * 8;
#pragma unroll
            for (int k = 0; k < 8; ++k)
                *(u16x8*)&eas[r][s * 8 + k * 32] = *(const u16x8*)(src + k * 32);
        } else {
            u16x8 z = {};
#pragma unroll
            for (int k = 0; k < 8; ++k) *(u16x8*)&eas[r][s * 8 + k * 32] = z;
        }
    }
    if (tid < 64) {
        long p = m0 + tid;
        cols_s[tid] = (p < E) ? colS[p] : -1;
        rows_s[tid] = (p < E) ? rowS[p] : 0;
    }
    __syncthreads();

    const int c = tid;
    float sum = 0.f;
    int cur = cols_s[0];
    int runstart = 0;
#pragma unroll 1
    for (int g = 0; g < 8; ++g) {
        float xv[8];
#pragma unroll
        for (int j = 0; j < 8; ++j)
            xv[j] = bf2f(XT[(long)rows_s[g * 8 + j] * 256 + c]);
#pragma unroll
        for (int j = 0; j < 8; ++j) {
            int e = g * 8 + j;
            int cc = cols_s[e];
            if (cc != cur) {
                if (cur >= 0) {
                    float* dst = AGG + (long)cur * 256 + c;
                    if (runstart > 0) *dst = sum;
                    else atomicAdd(dst, sum);
                }
                cur = cc; runstart = e; sum = 0.f;
            }
            sum += bf2f(eas[e][c]) * xv[j];
        }
    }
    if (cur >= 0) {
        atomicAdd(AGG + (long)cur * 256 + c, sum);
    }
}

// ---------------------------------------------------------------------------
// Message+reduce, N=32 (output layer).
// ---------------------------------------------------------------------------
__global__ __launch_bounds__(256) void msg32(
    const unsigned short* __restrict__ EAro, const unsigned short* __restrict__ XT,
    const int* __restrict__ rowS, const int* __restrict__ colS,
    const int* __restrict__ eidS, float* __restrict__ AGG, int E) {
    __shared__ __align__(16) unsigned short eas[256][36];
    __shared__ int rows_s[256];
    __shared__ int cols_s[256];
    __shared__ int eid_s[256];
    const int tid = threadIdx.x;
    const long m0 = (long)blockIdx.x * 256;

    {
        long p = m0 + tid;
        cols_s[tid] = (p < E) ? colS[p] : -1;
        rows_s[tid] = (p < E) ? rowS[p] : 0;
        eid_s[tid]  = (p < E) ? eidS[p] : -1;
    }
    __syncthreads();
    const int rr0 = tid >> 2, s = tid & 3;
#pragma unroll
    for (int ps = 0; ps < 4; ++ps) {
        int rr = ps * 64 + rr0;
        int eid = eid_s[rr];
        u16x8 v = {};
        if (eid >= 0) v = *(const u16x8*)(EAro + (long)eid * 32 + s * 8);
        *(u16x8*)&eas[rr][s * 8] = v;
    }
    __syncthreads();

    const int c = tid & 31, sb = tid >> 5;
    const int e0 = sb * 32;
    float sum = 0.f;
    int cur = cols_s[e0];
    int runstart = e0;
#pragma unroll 1
    for (int g = 0; g < 4; ++g) {
        float xv[8];
#pragma unroll
        for (int j = 0; j < 8; ++j)
            xv[j] = bf2f(XT[(long)rows_s[e0 + g * 8 + j] * 32 + c]);
#pragma unroll
        for (int j = 0; j < 8; ++j) {
            int e = e0 + g * 8 + j;
            int cc = cols_s[e];
            if (cc != cur) {
                if (cur >= 0) {
                    float* dst = AGG + (long)cur * 32 + c;
                    if (runstart > 0 && cols_s[runstart - 1] != cur) *dst = sum;
                    else atomicAdd(dst, sum);
                }
                cur = cc; runstart = e; sum = 0.f;
            }
            sum += bf2f(eas[e][c]) * xv[j];
        }
    }
    if (cur >= 0) {
        int eend = e0 + 32;
        float* dst = AGG + (long)cur * 32 + c;
        bool oks = (runstart > 0 && cols_s[runstart - 1] != cur);
        bool oke = (eend < 256 && cols_s[eend] != cur);
        if (oks && oke) *dst = sum;
        else atomicAdd(dst, sum);
    }
}

// ---------------------------------------------------------------------------
// Node GEMM for concat input, N=32.
// ---------------------------------------------------------------------------
__global__ __launch_bounds__(256) void node_cat_mfma(
    const float* __restrict__ X, const float* __restrict__ H0,
    const float* __restrict__ H1, const unsigned short* __restrict__ Wh,
    const float* __restrict__ bias, unsigned short* __restrict__ Y, int M) {
    __shared__ __align__(16) unsigned short As[4][256][8];
    __shared__ __align__(16) unsigned short Bs[4][32][8];
    const int tid = threadIdx.x;
    const int wv = tid >> 6, lane = tid & 63;
    const int l15 = lane & 15, l4 = lane >> 4;
    const long m0 = (long)blockIdx.x * 256;
    f32x4 acc[4][2] = {};

    const int sr = tid >> 3;
    const int sq = (tid & 7) * 4;
    const int sg2 = sq >> 3, so2 = sq & 7;

    for (int it = 0; it < 24; ++it) {
        const int k0 = it * 32;
        const float* src = (it < 8) ? X : (it < 16) ? H0 : H1;
        const int kk = k0 & 255;
        float4 va[8];
#pragma unroll
        for (int j = 0; j < 8; ++j) {
            long r_ = m0 + j * 32 + sr;
            va[j] = (r_ < M) ? *(const float4*)(src + r_ * 256 + kk + sq)
                             : make_float4(0.f, 0.f, 0.f, 0.f);
        }
        u16x8 bv = {};
        if (tid < 128)
            bv = *(const u16x8*)(Wh + (long)(tid >> 2) * 768 + k0 + (tid & 3) * 8);
        __syncthreads();
#pragma unroll
        for (int j = 0; j < 8; ++j) {
            u16x4 ap;
            ap[0] = f2bf(va[j].x); ap[1] = f2bf(va[j].y);
            ap[2] = f2bf(va[j].z); ap[3] = f2bf(va[j].w);
            *(u16x4*)&As[sg2][j * 32 + sr][so2] = ap;
        }
        if (tid < 128) *(u16x8*)&Bs[tid & 3][tid >> 2][0] = bv;
        __syncthreads();
        bf16x8 af[4], bfv[2];
#pragma unroll
        for (int mi = 0; mi < 4; ++mi)
            af[mi] = *(const bf16x8*)&As[l4][wv * 64 + mi * 16 + l15][0];
#pragma unroll
        for (int nj = 0; nj < 2; ++nj)
            bfv[nj] = *(const bf16x8*)&Bs[l4][nj * 16 + l15][0];
#pragma unroll
        for (int mi = 0; mi < 4; ++mi)
#pragma unroll
            for (int nj = 0; nj < 2; ++nj)
                acc[mi][nj] = __builtin_amdgcn_mfma_f32_16x16x32_bf16(
                    af[mi], bfv[nj], acc[mi][nj], 0, 0, 0);
    }

#pragma unroll
    for (int mi = 0; mi < 4; ++mi) {
#pragma unroll
        for (int r = 0; r < 4; ++r) {
            long gm = m0 + wv * 64 + mi * 16 + l4 * 4 + r;
            if (gm < M) {
#pragma unroll
                for (int nj = 0; nj < 2; ++nj) {
                    int o = nj * 16 + l15;
                    Y[gm * 32 + o] = f2bf(acc[mi][nj][r] + bias[o]);
                }
            }
        }
    }
}

// ---------------------------------------------------------------------------
// Small f32 KAN for output layer (M x 32 -> M x 32).
// ---------------------------------------------------------------------------
__global__ __launch_bounds__(256) void kan_gemm32(
    const float* __restrict__ AGG, const float* __restrict__ Wc,
    float* __restrict__ Y, int M) {
    __shared__ float As[64][36];
    __shared__ float Bs[32][36];
    const int tid = threadIdx.x;
    const int tx = tid & 15, ty = tid >> 4;
    const int m0 = blockIdx.x * 64;
    float acc[4][2] = {{0.f, 0.f}, {0.f, 0.f}, {0.f, 0.f}, {0.f, 0.f}};
    const int er = tid >> 2, ef = tid & 3;
    const int em = m0 + er;
    for (int ic = 0; ic < 32; ic += 4) {
        float xv = (em < M) ? AGG[(long)em * 32 + ic + ef] : 0.f;
        float e8[8];
        expand8(xv, e8);
        *(float4*)&As[er][ef * 8] = make_float4(e8[0], e8[1], e8[2], e8[3]);
        *(float4*)&As[er][ef * 8 + 4] = make_float4(e8[4], e8[5], e8[6], e8[7]);
        {
            int o = tid >> 3, k4 = (tid & 7) * 4;
            *(float4*)&Bs[o][k4] = *(const float4*)&Wc[(long)o * 256 + ic * 8 + k4];
        }
        __syncthreads();
#pragma unroll
        for (int kk = 0; kk < 32; ++kk) {
            float a_[4], b_[2];
#pragma unroll
            for (int i = 0; i < 4; ++i) a_[i] = As[ty * 4 + i][kk];
#pragma unroll
            for (int j = 0; j < 2; ++j) b_[j] = Bs[tx * 2 + j][kk];
#pragma unroll
            for (int i = 0; i < 4; ++i)
#pragma unroll
                for (int j = 0; j < 2; ++j) acc[i][j] = fmaf(a_[i], b_[j], acc[i][j]);
        }
        __syncthreads();
    }
#pragma unroll
    for (int i = 0; i < 4; ++i) {
        int gm = m0 + ty * 4 + i;
        if (gm >= M) continue;
#pragma unroll
        for (int j = 0; j < 2; ++j) Y[(long)gm * 32 + tx * 2 + j] = acc[i][j];
    }
}

// ---------------------------------------------------------------------------
// Misc weight prep
// ---------------------------------------------------------------------------
__global__ __launch_bounds__(256) void cvt_bf16(
    const float* __restrict__ s, unsigned short* __restrict__ d, int n) {
    int i = blockIdx.x * 256 + threadIdx.x;
    if (i < n) d[i] = f2bf(s[i]);
}

__global__ __launch_bounds__(256) void pack_kan_f32(
    const float* __restrict__ baseW, const float* __restrict__ splineW,
    float* __restrict__ Wc, int n) {
    int idx = blockIdx.x * 256 + threadIdx.x;
    if (idx >= n) return;
    float* dst = Wc + (long)idx * 8;
    dst[0] = baseW[idx];
    const float* sw = splineW + (long)idx * 7;
#pragma unroll
    for (int c = 0; c < 7; ++c) dst[1 + c] = sw[c];
}

// ---------------------------------------------------------------------------
extern "C" void kernel_launch(void* const* d_in, const int* in_sizes, int n_in,
                              void* d_out, int out_size, void* d_ws, size_t ws_size,
                              hipStream_t stream) {
    const float* x          = (const float*)d_in[0];
    const int*   edge_index = (const int*)d_in[1];
    const float* edge_attr  = (const float*)d_in[2];
    const float* node_W0 = (const float*)d_in[3];
    const float* node_b0 = (const float*)d_in[4];
    const float* edge_W0 = (const float*)d_in[5];
    const float* edge_b0 = (const float*)d_in[6];
    const float* base_W0 = (const float*)d_in[7];
    const float* spline_W0 = (const float*)d_in[8];
    const float* node_W1 = (const float*)d_in[9];
    const float* node_b1 = (const float*)d_in[10];
    const float* edge_W1 = (const float*)d_in[11];
    const float* edge_b1 = (const float*)d_in[12];
    const float* base_W1 = (const float*)d_in[13];
    const float* spline_W1 = (const float*)d_in[14];
    const float* node_Wo = (const float*)d_in[15];
    const float* node_bo = (const float*)d_in[16];
    const float* edge_Wo = (const float*)d_in[17];
    const float* edge_bo = (const float*)d_in[18];
    const float* base_Wo = (const float*)d_in[19];
    const float* spline_Wo = (const float*)d_in[20];
    float* out = (float*)d_out;

    const int N = in_sizes[0] / 256;
    const int E = in_sizes[1] / 2;

    float* ws  = (float*)d_ws;
    unsigned short* xt = (unsigned short*)ws;  // bf16 XT (slot sized N*256 f32)
    float* agg = ws + (long)N * 256;           // N*256 f32
    float* h0  = agg + (long)N * 256;
    float* h1  = h0 + (long)N * 256;
    float* Wco = h1 + (long)N * 256;           // 32*256 f32
    unsigned short* Wp0  = (unsigned short*)(Wco + 32 * 256);  // 98304
    unsigned short* Wp1  = Wp0 + 98304;
    unsigned short* Wpo  = Wp1 + 98304;                        // 12288
    unsigned short* nWp0 = Wpo + 12288;                        // 65536
    unsigned short* nWp1 = nWp0 + 65536;
    unsigned short* Wc0p = nWp1 + 65536;                       // 524288
    unsigned short* Wc1p = Wc0p + 524288;
    unsigned short* nWoh = Wc1p + 524288;                      // 24576
    int* cursor = (int*)(nWoh + 24576);
    int* rowS   = cursor + (N + 1);
    int* colS   = rowS + E;
    int* eidS   = colS + E;
    unsigned short* EAr0 = (unsigned short*)(((uintptr_t)(eidS + E) + 255) & ~(uintptr_t)255);
    const int nt256 = (E + 255) / 256;
    const long Epad = (long)nt256 * 256;
    unsigned short* EAr1 = EAr0 + Epad * 256;

    const size_t need2 = (size_t)((char*)(EAr1 + Epad * 256 + Epad * 32) - (char*)d_ws);
    const bool two = ws_size >= need2;
    unsigned short* EAro = two ? (EAr1 + Epad * 256) : (EAr0 + Epad * 256);

    const int* row = edge_index;
    const int* col = edge_index + E;

    const int nb64 = (N + 63) / 64;
    const int eb64 = (E + 63) / 64;
    const int eb256 = (E + 255) / 256;
    const int nb256 = (N + 255) / 256;

    // ---- counting sort of edges by destination ----
    hipMemsetAsync(cursor, 0, (size_t)(N + 1) * sizeof(int), stream);
    k_hist<<<eb256, 256, 0, stream>>>(col, cursor, E);
    k_scan<<<1, 1024, 0, stream>>>(cursor, N);
    k_scatter<<<eb256, 256, 0, stream>>>(row, col, cursor, rowS, colS, eidS, E);

    // ---- weight prep: K-step-tiled packs ----
    pack_kt<<<(256 * 384 + 255) / 256, 256, 0, stream>>>(edge_W0, Wp0, 256, 384);
    pack_kt<<<(256 * 384 + 255) / 256, 256, 0, stream>>>(edge_W1, Wp1, 256, 384);
    pack_kt<<<(32 * 384 + 255) / 256, 256, 0, stream>>>(edge_Wo, Wpo, 32, 384);
    pack_kt<<<(256 * 256 + 255) / 256, 256, 0, stream>>>(node_W0, nWp0, 256, 256);
    pack_kt<<<(256 * 256 + 255) / 256, 256, 0, stream>>>(node_W1, nWp1, 256, 256);
    pack_kan_kt<<<(256 * 2048 + 255) / 256, 256, 0, stream>>>(base_W0, spline_W0, Wc0p, 256);
    pack_kan_kt<<<(256 * 2048 + 255) / 256, 256, 0, stream>>>(base_W1, spline_W1, Wc1p, 256);
    cvt_bf16<<<(32 * 768 + 255) / 256, 256, 0, stream>>>(node_Wo, nWoh, 32 * 768);
    pack_kan_f32<<<(32 * 32 + 255) / 256, 256, 0, stream>>>(base_Wo, spline_Wo, Wco, 32 * 32);

    // ---- edge GEMMs (2 blocks/CU, depth-2 A pipeline, packed weights) ----
    if (two) {
        ea_gemm7<true, true><<<eb64, 256, 0, stream>>>(
            edge_attr, Wp0, edge_b0, Wp1, edge_b1, Wpo, edge_bo,
            EAr0, EAr1, EAro, E);
    } else {
        ea_gemm7<false, true><<<eb64, 256, 0, stream>>>(
            edge_attr, Wp0, edge_b0, Wp0, edge_b0, Wpo, edge_bo,
            EAr0, EAr0, EAro, E);
    }

    // ---- layer 0 ----
    hipMemsetAsync(agg, 0, (size_t)N * 256 * sizeof(float), stream);
    node_mfma_p<256><<<nb64, 256, 0, stream>>>(x, nWp0, node_b0, xt, N);
    msg256<<<eb64, 256, 0, stream>>>(EAr0, xt, rowS, colS, eidS, agg, E);
    kan_mfma256_p<<<nb64, 256, 0, stream>>>(agg, Wc0p, h0, N);

    // ---- layer 1 ----
    if (!two) {
        ea_gemm7<false, false><<<eb64, 256, 0, stream>>>(
            edge_attr, Wp1, edge_b1, Wp1, edge_b1, Wpo, edge_bo,
            EAr0, EAr0, EAro, E);
    }
    hipMemsetAsync(agg, 0, (size_t)N * 256 * sizeof(float), stream);
    node_mfma_p<256><<<nb64, 256, 0, stream>>>(h0, nWp1, node_b1, xt, N);
    msg256<<<eb64, 256, 0, stream>>>(two ? EAr1 : EAr0, xt, rowS, colS, eidS, agg, E);
    kan_mfma256_p<<<nb64, 256, 0, stream>>>(agg, Wc1p, h1, N);

    // ---- output layer ----
    hipMemsetAsync(agg, 0, (size_t)N * 32 * sizeof(float), stream);
    node_cat_mfma<<<nb256, 256, 0, stream>>>(x, h0, h1, nWoh, node_bo, xt, N);
    msg32<<<eb256, 256, 0, stream>>>(EAro, xt, rowS, colS, eidS, agg, E);
    kan_gemm32<<<nb64, 256, 0, stream>>>(agg, Wco, out, N);
}